// Round 3
// baseline (1154.854 us; speedup 1.0000x reference)
//
#include <hip/hip_runtime.h>
#include <hip/hip_bf16.h>

#define BQ 4
#define HH 56
#define WW 56
#define NN (HH*WW)      // 3136
#define CC 256
#define NHEAD 8
#define HD 32
#define PP 1376
#define HIDN 1024
#define EPS_LN 1e-5f
#define ATT_SCALE 0.17677669529663687f

typedef unsigned short bf16u;

__device__ __forceinline__ float bf2f(bf16u u){
  union { unsigned int i; float f; } v; v.i = ((unsigned int)u) << 16; return v.f;
}
__device__ __forceinline__ bf16u f2bf(float f){
  unsigned int x = __float_as_uint(f);
  x += 0x7fffu + ((x >> 16) & 1u);
  return (bf16u)(x >> 16);
}

// ---------------- CPE: x1 = x + dwconv3x3(x) + bias   (channel-last, f32) ----------------
__global__ void k_cpe(const float* __restrict__ x, const float* __restrict__ w,
                      const float* __restrict__ bias, float* __restrict__ x1){
  int bn = blockIdx.x;
  int b = bn / NN, n = bn % NN;
  int hy = n / WW, wx = n % WW;
  int c = threadIdx.x;
  float wv[9];
#pragma unroll
  for (int k = 0; k < 9; k++) wv[k] = w[c*9+k];
  float acc = bias[c];
  const float* xb = x + (size_t)b*NN*CC + c;
#pragma unroll
  for (int kh = 0; kh < 3; kh++){
    int iy = hy + kh - 1;
    if (iy < 0 || iy >= HH) continue;
#pragma unroll
    for (int kw = 0; kw < 3; kw++){
      int ix = wx + kw - 1;
      if (ix < 0 || ix >= WW) continue;
      acc += xb[(size_t)(iy*WW+ix)*CC] * wv[kh*3+kw];
    }
  }
  float center = xb[(size_t)n*CC];
  x1[(size_t)bn*CC + c] = center + acc;
}

// ---------------- LayerNorm over C=256, one row per block ----------------
__global__ void k_ln(const float* __restrict__ X, const float* __restrict__ g,
                     const float* __restrict__ be, float* Y){
  int row = blockIdx.x;
  int t = threadIdx.x;
  float v = X[(size_t)row*CC + t];
  float s = v, s2 = v*v;
#pragma unroll
  for (int off = 32; off; off >>= 1){
    s  += __shfl_down(s,  off, 64);
    s2 += __shfl_down(s2, off, 64);
  }
  __shared__ float red[10];
  int wv_ = t >> 6, ln = t & 63;
  if (ln == 0){ red[wv_] = s; red[4+wv_] = s2; }
  __syncthreads();
  if (t == 0){
    float S  = red[0]+red[1]+red[2]+red[3];
    float S2 = red[4]+red[5]+red[6]+red[7];
    float mean = S * (1.f/CC);
    float var  = S2 * (1.f/CC) - mean*mean;
    red[8] = mean; red[9] = rsqrtf(var + EPS_LN);
  }
  __syncthreads();
  float mean = red[8], rstd = red[9];
  Y[(size_t)row*CC + t] = (v - mean) * rstd * g[t] + be[t];
}

// ---------------- adaptive avg pool (one (b,p) per block, c = thread) ----------------
__global__ void k_pool(const float* __restrict__ xn, float* __restrict__ praw){
  int bp = blockIdx.x;
  int b = bp / PP, p = bp % PP;
  int ps, pi;
  if (p < 144)      { ps = 12; pi = p; }
  else if (p < 400) { ps = 16; pi = p - 144; }
  else if (p < 800) { ps = 20; pi = p - 400; }
  else              { ps = 24; pi = p - 800; }
  int oi = pi / ps, oj = pi % ps;
  int si = oi*HH/ps, ei = ((oi+1)*HH + ps - 1)/ps;
  int sj = oj*WW/ps, ej = ((oj+1)*WW + ps - 1)/ps;
  int c = threadIdx.x;
  const float* xb = xn + (size_t)b*NN*CC + c;
  float acc = 0.f;
  for (int i = si; i < ei; i++)
    for (int j = sj; j < ej; j++)
      acc += xb[(size_t)(i*WW+j)*CC];
  praw[(size_t)bp*CC + c] = acc / (float)((ei-si)*(ej-sj));
}

// ---------------- pools = praw + dwconv3x3(praw) + bias (per level) ----------------
__global__ void k_pool_dw(const float* __restrict__ praw,
    const float* w0, const float* b0, const float* w1, const float* b1,
    const float* w2, const float* b2, const float* w3, const float* b3,
    float* __restrict__ pools){
  int bp = blockIdx.x;
  int b = bp / PP, p = bp % PP;
  int ps, pi, off; const float *w, *bi;
  if (p < 144)      { ps=12; pi=p;     off=0;   w=w0; bi=b0; }
  else if (p < 400) { ps=16; pi=p-144; off=144; w=w1; bi=b1; }
  else if (p < 800) { ps=20; pi=p-400; off=400; w=w2; bi=b2; }
  else              { ps=24; pi=p-800; off=800; w=w3; bi=b3; }
  int oi = pi/ps, oj = pi%ps;
  int c = threadIdx.x;
  const float* base = praw + (size_t)(b*PP + off)*CC + c;
  float acc = bi[c];
#pragma unroll
  for (int kh = 0; kh < 3; kh++){
    int ii = oi + kh - 1; if (ii < 0 || ii >= ps) continue;
#pragma unroll
    for (int kw = 0; kw < 3; kw++){
      int jj = oj + kw - 1; if (jj < 0 || jj >= ps) continue;
      acc += base[(size_t)(ii*ps+jj)*CC] * w[c*9 + kh*3 + kw];
    }
  }
  float center = base[(size_t)(oi*ps+oj)*CC];
  pools[(size_t)bp*CC + c] = center + acc;
}

// --------- generic tiled GEMM: Out[M,Nout] = act(A[M,K] @ Wt[Nout,K]^T + bias) + Res ------
template<bool TA_BF16, bool OUT_BF16, bool HAS_BIAS, bool DO_GELU, bool HAS_RES>
__global__ __launch_bounds__(256) void k_gemm(const void* __restrict__ Ap,
                       const float* __restrict__ Wt,
                       const float* __restrict__ bias, void* Outp,
                       const float* Res, int M, int Nout, int K){
  __shared__ float As[16][68];
  __shared__ float Bs[16][68];
  int t = threadIdx.x;
  int m0 = blockIdx.y * 64, n0 = blockIdx.x * 64;
  int lr = t >> 2, lq = t & 3;
  int tx = t & 15, ty = t >> 4;
  float acc[4][4] = {};
  for (int k0 = 0; k0 < K; k0 += 16){
    float a0,a1,a2,a3;
    if constexpr (TA_BF16){
      const bf16u* ap = (const bf16u*)Ap + (size_t)(m0+lr)*K + k0 + lq*4;
      ushort4 u = *(const ushort4*)ap;
      a0 = bf2f(u.x); a1 = bf2f(u.y); a2 = bf2f(u.z); a3 = bf2f(u.w);
    } else {
      const float* ap = (const float*)Ap + (size_t)(m0+lr)*K + k0 + lq*4;
      float4 u = *(const float4*)ap;
      a0 = u.x; a1 = u.y; a2 = u.z; a3 = u.w;
    }
    As[lq*4+0][lr]=a0; As[lq*4+1][lr]=a1; As[lq*4+2][lr]=a2; As[lq*4+3][lr]=a3;
    {
      const float* bp = Wt + (size_t)(n0+lr)*K + k0 + lq*4;
      float4 u = *(const float4*)bp;
      Bs[lq*4+0][lr]=u.x; Bs[lq*4+1][lr]=u.y;
      Bs[lq*4+2][lr]=u.z; Bs[lq*4+3][lr]=u.w;
    }
    __syncthreads();
#pragma unroll
    for (int kk = 0; kk < 16; kk++){
      float4 av = *(const float4*)&As[kk][ty*4];
      float4 bv = *(const float4*)&Bs[kk][tx*4];
      acc[0][0] += av.x*bv.x; acc[0][1] += av.x*bv.y; acc[0][2] += av.x*bv.z; acc[0][3] += av.x*bv.w;
      acc[1][0] += av.y*bv.x; acc[1][1] += av.y*bv.y; acc[1][2] += av.y*bv.z; acc[1][3] += av.y*bv.w;
      acc[2][0] += av.z*bv.x; acc[2][1] += av.z*bv.y; acc[2][2] += av.z*bv.z; acc[2][3] += av.z*bv.w;
      acc[3][0] += av.w*bv.x; acc[3][1] += av.w*bv.y; acc[3][2] += av.w*bv.z; acc[3][3] += av.w*bv.w;
    }
    __syncthreads();
  }
#pragma unroll
  for (int i = 0; i < 4; i++){
    int row = m0 + ty*4 + i;
#pragma unroll
    for (int j = 0; j < 4; j++){
      int col = n0 + tx*4 + j;
      float v = acc[i][j];
      if constexpr (HAS_BIAS) v += bias[col];
      if constexpr (DO_GELU)  v = 0.5f*v*(1.f + erff(v*0.70710678118654752f));
      if constexpr (HAS_RES)  v += Res[(size_t)row*Nout + col];
      if constexpr (OUT_BF16) ((bf16u*)Outp)[(size_t)row*Nout + col] = f2bf(v);
      else                    ((float*)Outp)[(size_t)row*Nout + col] = v;
    }
  }
}

// ---------------- flash attention: 16 queries/block, 64-key LDS chunks ----------------
// writes output IN PLACE into q (each block touches only its own (rows, head) slice)
__global__ __launch_bounds__(256) void k_attn(float* __restrict__ q,
                       const float* __restrict__ kv){
  __shared__ float qs[16][36];
  __shared__ float ks[64][36];
  __shared__ float vs[64][36];
  __shared__ float ss[16][68];
  int t = threadIdx.x;
  int bid = blockIdx.x;
  int qt = bid % (NN/16);
  int hh = (bid / (NN/16)) % NHEAD;
  int b  = bid / ((NN/16)*NHEAD);
  int q0 = qt*16;
  {
    int qq = t >> 4;
    int d  = (t & 15) * 2;
    const float* src = q + (size_t)(b*NN + q0 + qq)*CC + hh*HD + d;
    float2 v = *(const float2*)src;
    qs[qq][d] = v.x; qs[qq][d+1] = v.y;
  }
  __syncthreads();
  int myq = t >> 4;
  int lane16 = t & 15;
  int d0 = lane16*2;
  float qr[32];
#pragma unroll
  for (int k4 = 0; k4 < 8; k4++){
    float4 v = *(const float4*)&qs[myq][k4*4];
    qr[k4*4]=v.x; qr[k4*4+1]=v.y; qr[k4*4+2]=v.z; qr[k4*4+3]=v.w;
  }
  float m = -1e30f, l = 0.f, o0 = 0.f, o1 = 0.f;
  const int nch = (PP + 63)/64;   // 22
  for (int ch = 0; ch < nch; ch++){
    int p0 = ch*64;
    {
      int row = t >> 2;
      int dc  = (t & 3) * 8;
      int p = p0 + row;
      if (p < PP){
        const float* sk = kv + (size_t)(b*PP + p)*(2*CC) + hh*HD + dc;
        float4 a = *(const float4*)sk;
        float4 c = *(const float4*)(sk+4);
        ks[row][dc+0]=a.x; ks[row][dc+1]=a.y; ks[row][dc+2]=a.z; ks[row][dc+3]=a.w;
        ks[row][dc+4]=c.x; ks[row][dc+5]=c.y; ks[row][dc+6]=c.z; ks[row][dc+7]=c.w;
        const float* sv = sk + CC;
        float4 e4 = *(const float4*)sv;
        float4 f4 = *(const float4*)(sv+4);
        vs[row][dc+0]=e4.x; vs[row][dc+1]=e4.y; vs[row][dc+2]=e4.z; vs[row][dc+3]=e4.w;
        vs[row][dc+4]=f4.x; vs[row][dc+5]=f4.y; vs[row][dc+6]=f4.z; vs[row][dc+7]=f4.w;
      } else {
#pragma unroll
        for (int j = 0; j < 8; j++){ ks[row][dc+j]=0.f; vs[row][dc+j]=0.f; }
      }
    }
    __syncthreads();
    float e[4];
    float mc = -1e30f;
#pragma unroll
    for (int pp = 0; pp < 4; pp++){
      int pl = lane16 + pp*16;
      float s = 0.f;
#pragma unroll
      for (int k4 = 0; k4 < 8; k4++){
        float4 kvv = *(const float4*)&ks[pl][k4*4];
        s += qr[k4*4]*kvv.x + qr[k4*4+1]*kvv.y + qr[k4*4+2]*kvv.z + qr[k4*4+3]*kvv.w;
      }
      s *= ATT_SCALE;
      if (p0 + pl >= PP) s = -1e30f;
      e[pp] = s;
      mc = fmaxf(mc, s);
    }
#pragma unroll
    for (int off = 8; off; off >>= 1) mc = fmaxf(mc, __shfl_xor(mc, off, 16));
    float nm = fmaxf(m, mc);
    float alpha = __expf(m - nm);
    float lsum = 0.f;
#pragma unroll
    for (int pp = 0; pp < 4; pp++){
      float ev = __expf(e[pp] - nm);
      lsum += ev;
      ss[myq][lane16 + pp*16] = ev;
    }
#pragma unroll
    for (int off = 8; off; off >>= 1) lsum += __shfl_xor(lsum, off, 16);
    l = l*alpha + lsum;
    m = nm;
    o0 *= alpha; o1 *= alpha;
    __syncthreads();
#pragma unroll 4
    for (int p4 = 0; p4 < 16; p4++){
      float4 w4 = *(const float4*)&ss[myq][p4*4];
      float2 v0 = *(const float2*)&vs[p4*4+0][d0];
      float2 v1 = *(const float2*)&vs[p4*4+1][d0];
      float2 v2 = *(const float2*)&vs[p4*4+2][d0];
      float2 v3 = *(const float2*)&vs[p4*4+3][d0];
      o0 += w4.x*v0.x + w4.y*v1.x + w4.z*v2.x + w4.w*v3.x;
      o1 += w4.x*v0.y + w4.y*v1.y + w4.z*v2.y + w4.w*v3.y;
    }
    __syncthreads();
  }
  float inv = 1.f / l;
  float2 outv; outv.x = o0*inv; outv.y = o1*inv;
  *(float2*)(q + (size_t)(b*NN + q0 + myq)*CC + hh*HD + d0) = outv;
}

// ---------------- h2 = h + dwconv3x3(h) + bias  (hid=1024, h in bf16, w f32) ----------------
__global__ void k_dwh(const bf16u* __restrict__ h, const float* __restrict__ w,
                      const float* __restrict__ bias, bf16u* __restrict__ h2){
  int bn = blockIdx.x;
  int b = bn / NN, n = bn % NN;
  int hy = n / WW, wx = n % WW;
  const bf16u* hb = h + (size_t)b*NN*HIDN;
#pragma unroll
  for (int ci = 0; ci < 4; ci++){
    int c = threadIdx.x + ci*256;
    float acc = bias[c];
#pragma unroll
    for (int kh = 0; kh < 3; kh++){
      int iy = hy + kh - 1; if (iy < 0 || iy >= HH) continue;
#pragma unroll
      for (int kw = 0; kw < 3; kw++){
        int ix = wx + kw - 1; if (ix < 0 || ix >= WW) continue;
        acc += bf2f(hb[(size_t)(iy*WW+ix)*HIDN + c]) * w[c*9 + kh*3 + kw];
      }
    }
    float center = bf2f(hb[(size_t)n*HIDN + c]);
    h2[(size_t)bn*HIDN + c] = f2bf(center + acc);
  }
}

extern "C" void kernel_launch(void* const* d_in, const int* in_sizes, int n_in,
                              void* d_out, int out_size, void* d_ws, size_t ws_size,
                              hipStream_t stream){
  const float* x      = (const float*)d_in[0];
  const float* cpe_w  = (const float*)d_in[1];
  const float* cpe_b  = (const float*)d_in[2];
  const float* n1w    = (const float*)d_in[3];
  const float* n1b    = (const float*)d_in[4];
  const float* q_w    = (const float*)d_in[5];
  const float* kv_w   = (const float*)d_in[6];
  const float* anw    = (const float*)d_in[7];
  const float* anb    = (const float*)d_in[8];
  const float* proj_w = (const float*)d_in[9];
  const float* proj_b = (const float*)d_in[10];
  const float* n2w    = (const float*)d_in[11];
  const float* n2b    = (const float*)d_in[12];
  const float* fc1_w  = (const float*)d_in[13];
  const float* fc1_b  = (const float*)d_in[14];
  const float* irb_w  = (const float*)d_in[15];
  const float* irb_b  = (const float*)d_in[16];
  const float* fc2_w  = (const float*)d_in[17];
  const float* fc2_b  = (const float*)d_in[18];
  const float* dw0    = (const float*)d_in[21];
  const float* db0    = (const float*)d_in[22];
  const float* dw1    = (const float*)d_in[23];
  const float* db1    = (const float*)d_in[24];
  const float* dw2    = (const float*)d_in[25];
  const float* db2    = (const float*)d_in[26];
  const float* dw3    = (const float*)d_in[27];
  const float* db3    = (const float*)d_in[28];

  // workspace layout (with reuse):
  //   x1 [B*N*C f32]  | xn [B*N*C f32]  | region R
  //   R phase 1 (steps 3-8): qb [B*N*C f32] praw [B*P*C f32] pools [B*P*C f32] kvb [B*P*2C f32]
  //   R phase 2 (steps 10-12): hbuf [B*N*HIDN bf16] h2buf [B*N*HIDN bf16]   (qb.. all dead)
  float* ws     = (float*)d_ws;
  float* x1     = ws;
  float* xn     = x1     + (size_t)BQ*NN*CC;
  float* qb     = xn     + (size_t)BQ*NN*CC;
  float* praw   = qb     + (size_t)BQ*NN*CC;
  float* pools  = praw   + (size_t)BQ*PP*CC;
  float* kvb    = pools  + (size_t)BQ*PP*CC;
  bf16u* hbuf   = (bf16u*)qb;                    // reuse: qb dead after step 8
  bf16u* h2buf  = hbuf + (size_t)BQ*NN*HIDN;

  // 1. CPE + residual
  k_cpe<<<BQ*NN, 256, 0, stream>>>(x, cpe_w, cpe_b, x1);
  // 2. norm1
  k_ln<<<BQ*NN, 256, 0, stream>>>(x1, n1w, n1b, xn);
  // 3. q projection
  k_gemm<false,false,false,false,false><<<dim3(CC/64, BQ*NN/64), 256, 0, stream>>>(
      xn, q_w, nullptr, qb, nullptr, BQ*NN, CC, CC);
  // 4. pyramid pooling
  k_pool<<<BQ*PP, 256, 0, stream>>>(xn, praw);
  k_pool_dw<<<BQ*PP, 256, 0, stream>>>(praw, dw0,db0, dw1,db1, dw2,db2, dw3,db3, pools);
  // 5. attn-norm (in-place)
  k_ln<<<BQ*PP, 256, 0, stream>>>(pools, anw, anb, pools);
  // 6. kv projection
  k_gemm<false,false,false,false,false><<<dim3(2*CC/64, BQ*PP/64), 256, 0, stream>>>(
      pools, kv_w, nullptr, kvb, nullptr, BQ*PP, 2*CC, CC);
  // 7. attention (in-place: qb becomes attn output)
  k_attn<<<BQ*NHEAD*(NN/16), 256, 0, stream>>>(qb, kvb);
  // 8. proj + bias + residual (into x1, in-place residual)
  k_gemm<false,false,true,false,true><<<dim3(CC/64, BQ*NN/64), 256, 0, stream>>>(
      qb, proj_w, proj_b, x1, x1, BQ*NN, CC, CC);
  // 9. norm2
  k_ln<<<BQ*NN, 256, 0, stream>>>(x1, n2w, n2b, xn);
  // 10. fc1 + bias + gelu -> h (bf16)
  k_gemm<false,true,true,true,false><<<dim3(HIDN/64, BQ*NN/64), 256, 0, stream>>>(
      xn, fc1_w, fc1_b, hbuf, nullptr, BQ*NN, HIDN, CC);
  // 11. h2 = h + dwconv(h)
  k_dwh<<<BQ*NN, 256, 0, stream>>>(hbuf, irb_w, irb_b, h2buf);
  // 12. fc2 + bias + residual -> d_out (f32!)
  k_gemm<true,false,true,false,true><<<dim3(CC/64, BQ*NN/64), 256, 0, stream>>>(
      h2buf, fc2_w, fc2_b, d_out, x1, BQ*NN, CC, HIDN);
}

// Round 4
// 665.418 us; speedup vs baseline: 1.7355x; 1.7355x over previous
//
#include <hip/hip_runtime.h>
#include <hip/hip_bf16.h>

#define BQ 4
#define HH 56
#define WW 56
#define NN (HH*WW)      // 3136
#define CC 256
#define NHEAD 8
#define HD 32
#define PP 1376
#define HIDN 1024
#define EPS_LN 1e-5f
#define ATT_SCALE 0.17677669529663687f

typedef unsigned short bf16u;
typedef __attribute__((ext_vector_type(8))) short short8;
typedef __attribute__((ext_vector_type(4))) float f32x4;

__device__ __forceinline__ float bf2f(bf16u u){
  union { unsigned int i; float f; } v; v.i = ((unsigned int)u) << 16; return v.f;
}
__device__ __forceinline__ bf16u f2bf(float f){
  unsigned int x = __float_as_uint(f);
  x += 0x7fffu + ((x >> 16) & 1u);
  return (bf16u)(x >> 16);
}

// ---------------- CPE: x1 = x + dwconv3x3(x) + bias   (channel-last, f32) ----------------
__global__ void k_cpe(const float* __restrict__ x, const float* __restrict__ w,
                      const float* __restrict__ bias, float* __restrict__ x1){
  int bn = blockIdx.x;
  int b = bn / NN, n = bn % NN;
  int hy = n / WW, wx = n % WW;
  int c = threadIdx.x;
  float wv[9];
#pragma unroll
  for (int k = 0; k < 9; k++) wv[k] = w[c*9+k];
  float acc = bias[c];
  const float* xb = x + (size_t)b*NN*CC + c;
#pragma unroll
  for (int kh = 0; kh < 3; kh++){
    int iy = hy + kh - 1;
    if (iy < 0 || iy >= HH) continue;
#pragma unroll
    for (int kw = 0; kw < 3; kw++){
      int ix = wx + kw - 1;
      if (ix < 0 || ix >= WW) continue;
      acc += xb[(size_t)(iy*WW+ix)*CC] * wv[kh*3+kw];
    }
  }
  float center = xb[(size_t)n*CC];
  x1[(size_t)bn*CC + c] = center + acc;
}

// ---------------- LayerNorm over C=256, one row per block ----------------
__global__ void k_ln(const float* __restrict__ X, const float* __restrict__ g,
                     const float* __restrict__ be, float* Y){
  int row = blockIdx.x;
  int t = threadIdx.x;
  float v = X[(size_t)row*CC + t];
  float s = v, s2 = v*v;
#pragma unroll
  for (int off = 32; off; off >>= 1){
    s  += __shfl_down(s,  off, 64);
    s2 += __shfl_down(s2, off, 64);
  }
  __shared__ float red[10];
  int wv_ = t >> 6, ln = t & 63;
  if (ln == 0){ red[wv_] = s; red[4+wv_] = s2; }
  __syncthreads();
  if (t == 0){
    float S  = red[0]+red[1]+red[2]+red[3];
    float S2 = red[4]+red[5]+red[6]+red[7];
    float mean = S * (1.f/CC);
    float var  = S2 * (1.f/CC) - mean*mean;
    red[8] = mean; red[9] = rsqrtf(var + EPS_LN);
  }
  __syncthreads();
  float mean = red[8], rstd = red[9];
  Y[(size_t)row*CC + t] = (v - mean) * rstd * g[t] + be[t];
}

// ---------------- adaptive avg pool (one (b,p) per block, c = thread) ----------------
__global__ void k_pool(const float* __restrict__ xn, float* __restrict__ praw){
  int bp = blockIdx.x;
  int b = bp / PP, p = bp % PP;
  int ps, pi;
  if (p < 144)      { ps = 12; pi = p; }
  else if (p < 400) { ps = 16; pi = p - 144; }
  else if (p < 800) { ps = 20; pi = p - 400; }
  else              { ps = 24; pi = p - 800; }
  int oi = pi / ps, oj = pi % ps;
  int si = oi*HH/ps, ei = ((oi+1)*HH + ps - 1)/ps;
  int sj = oj*WW/ps, ej = ((oj+1)*WW + ps - 1)/ps;
  int c = threadIdx.x;
  const float* xb = xn + (size_t)b*NN*CC + c;
  float acc = 0.f;
  for (int i = si; i < ei; i++)
    for (int j = sj; j < ej; j++)
      acc += xb[(size_t)(i*WW+j)*CC];
  praw[(size_t)bp*CC + c] = acc / (float)((ei-si)*(ej-sj));
}

// ---------------- pools = praw + dwconv3x3(praw) + bias (per level) ----------------
__global__ void k_pool_dw(const float* __restrict__ praw,
    const float* w0, const float* b0, const float* w1, const float* b1,
    const float* w2, const float* b2, const float* w3, const float* b3,
    float* __restrict__ pools){
  int bp = blockIdx.x;
  int b = bp / PP, p = bp % PP;
  int ps, pi, off; const float *w, *bi;
  if (p < 144)      { ps=12; pi=p;     off=0;   w=w0; bi=b0; }
  else if (p < 400) { ps=16; pi=p-144; off=144; w=w1; bi=b1; }
  else if (p < 800) { ps=20; pi=p-400; off=400; w=w2; bi=b2; }
  else              { ps=24; pi=p-800; off=800; w=w3; bi=b3; }
  int oi = pi/ps, oj = pi%ps;
  int c = threadIdx.x;
  const float* base = praw + (size_t)(b*PP + off)*CC + c;
  float acc = bi[c];
#pragma unroll
  for (int kh = 0; kh < 3; kh++){
    int ii = oi + kh - 1; if (ii < 0 || ii >= ps) continue;
#pragma unroll
    for (int kw = 0; kw < 3; kw++){
      int jj = oj + kw - 1; if (jj < 0 || jj >= ps) continue;
      acc += base[(size_t)(ii*ps+jj)*CC] * w[c*9 + kh*3 + kw];
    }
  }
  float center = base[(size_t)(oi*ps+oj)*CC];
  pools[(size_t)bp*CC + c] = center + acc;
}

// --------- generic tiled GEMM: Out[M,Nout] = act(A[M,K] @ Wt[Nout,K]^T + bias) + Res ------
template<bool TA_BF16, bool OUT_BF16, bool HAS_BIAS, bool DO_GELU, bool HAS_RES>
__global__ __launch_bounds__(256) void k_gemm(const void* __restrict__ Ap,
                       const float* __restrict__ Wt,
                       const float* __restrict__ bias, void* Outp,
                       const float* Res, int M, int Nout, int K){
  __shared__ float As[16][68];
  __shared__ float Bs[16][68];
  int t = threadIdx.x;
  int m0 = blockIdx.y * 64, n0 = blockIdx.x * 64;
  int lr = t >> 2, lq = t & 3;
  int tx = t & 15, ty = t >> 4;
  float acc[4][4] = {};
  for (int k0 = 0; k0 < K; k0 += 16){
    float a0,a1,a2,a3;
    if constexpr (TA_BF16){
      const bf16u* ap = (const bf16u*)Ap + (size_t)(m0+lr)*K + k0 + lq*4;
      ushort4 u = *(const ushort4*)ap;
      a0 = bf2f(u.x); a1 = bf2f(u.y); a2 = bf2f(u.z); a3 = bf2f(u.w);
    } else {
      const float* ap = (const float*)Ap + (size_t)(m0+lr)*K + k0 + lq*4;
      float4 u = *(const float4*)ap;
      a0 = u.x; a1 = u.y; a2 = u.z; a3 = u.w;
    }
    As[lq*4+0][lr]=a0; As[lq*4+1][lr]=a1; As[lq*4+2][lr]=a2; As[lq*4+3][lr]=a3;
    {
      const float* bp = Wt + (size_t)(n0+lr)*K + k0 + lq*4;
      float4 u = *(const float4*)bp;
      Bs[lq*4+0][lr]=u.x; Bs[lq*4+1][lr]=u.y;
      Bs[lq*4+2][lr]=u.z; Bs[lq*4+3][lr]=u.w;
    }
    __syncthreads();
#pragma unroll
    for (int kk = 0; kk < 16; kk++){
      float4 av = *(const float4*)&As[kk][ty*4];
      float4 bv = *(const float4*)&Bs[kk][tx*4];
      acc[0][0] += av.x*bv.x; acc[0][1] += av.x*bv.y; acc[0][2] += av.x*bv.z; acc[0][3] += av.x*bv.w;
      acc[1][0] += av.y*bv.x; acc[1][1] += av.y*bv.y; acc[1][2] += av.y*bv.z; acc[1][3] += av.y*bv.w;
      acc[2][0] += av.z*bv.x; acc[2][1] += av.z*bv.y; acc[2][2] += av.z*bv.z; acc[2][3] += av.z*bv.w;
      acc[3][0] += av.w*bv.x; acc[3][1] += av.w*bv.y; acc[3][2] += av.w*bv.z; acc[3][3] += av.w*bv.w;
    }
    __syncthreads();
  }
#pragma unroll
  for (int i = 0; i < 4; i++){
    int row = m0 + ty*4 + i;
#pragma unroll
    for (int j = 0; j < 4; j++){
      int col = n0 + tx*4 + j;
      float v = acc[i][j];
      if constexpr (HAS_BIAS) v += bias[col];
      if constexpr (DO_GELU)  v = 0.5f*v*(1.f + erff(v*0.70710678118654752f));
      if constexpr (HAS_RES)  v += Res[(size_t)row*Nout + col];
      if constexpr (OUT_BF16) ((bf16u*)Outp)[(size_t)row*Nout + col] = f2bf(v);
      else                    ((float*)Outp)[(size_t)row*Nout + col] = v;
    }
  }
}

// ============ MFMA flash attention ============
// 64 queries/block (16 per wave), 32-key chunks. q,kv in bf16.
// No max-subtraction (scores are small: |s| < ~4), so l-sum accumulates per-lane
// and is reduced once at the end; O accumulates in MFMA C-regs with no rescaling.
// Layouts (m89/m120-verified): C/D: row(m)=quad*4+reg, col(n)=lane&15.
//                              A: [m=lane&15][k=quad*8+j]. B: [n=lane&15][k=quad*8+j].
#define KS 40   // LDS row strides in bf16 elems (80B: 16B-aligned, 2-way banks = free)
#define VS 40
#define PS 40
__global__ __launch_bounds__(256) void k_attn_mfma(const bf16u* __restrict__ q,
                       const bf16u* __restrict__ kv, bf16u* __restrict__ out){
  __shared__ bf16u Ksh[32*KS];      // [key][dim]
  __shared__ bf16u Vsh[32*VS];      // [dim][key]  (V transposed)
  __shared__ bf16u Psh[4][16*PS];   // per-wave P  [query][key]
  int t = threadIdx.x;
  int wave = t >> 6, lane = t & 63;
  int quad = lane >> 4, l16 = lane & 15;
  int bid = blockIdx.x;
  int qt = bid % (NN/64);
  int hh = (bid / (NN/64)) % NHEAD;
  int b  = bid / ((NN/64)*NHEAD);
  int q0 = qt*64 + wave*16;
  // Q A-frag: Q[q0+l16][hh*32 + quad*8 + j], j=0..7 (16B aligned)
  short8 qfrag = *(const short8*)(q + ((size_t)(b*NN + q0 + l16)*CC + hh*HD + quad*8));
  f32x4 zero = {0.f,0.f,0.f,0.f};
  f32x4 o0 = zero, o1 = zero;
  float lsum[4] = {0.f,0.f,0.f,0.f};
  // staging indices: 256 threads load 32 keys x 32 dims of K and V
  int sp = t & 31, sd0 = (t >> 5) * 4;
  for (int ch = 0; ch < PP/32; ch++){
    int p0 = ch*32;
    __syncthreads();
    {
      const bf16u* src = kv + ((size_t)(b*PP + p0 + sp)*(2*CC) + hh*HD + sd0);
      ushort4 kk = *(const ushort4*)src;
      ushort4 vv = *(const ushort4*)(src + CC);
      *(ushort4*)(&Ksh[sp*KS + sd0]) = kk;
      Vsh[(sd0+0)*VS + sp] = vv.x;
      Vsh[(sd0+1)*VS + sp] = vv.y;
      Vsh[(sd0+2)*VS + sp] = vv.z;
      Vsh[(sd0+3)*VS + sp] = vv.w;
    }
    __syncthreads();
    // QK^T: scores [16q x 32keys]
    short8 kf0 = *(const short8*)(&Ksh[(l16     )*KS + quad*8]);
    short8 kf1 = *(const short8*)(&Ksh[(l16 + 16)*KS + quad*8]);
    f32x4 s0 = __builtin_amdgcn_mfma_f32_16x16x32_bf16(qfrag, kf0, zero, 0,0,0);
    f32x4 s1 = __builtin_amdgcn_mfma_f32_16x16x32_bf16(qfrag, kf1, zero, 0,0,0);
    // exp + P write (C-layout -> LDS [query][key])
#pragma unroll
    for (int r = 0; r < 4; r++){
      float e0 = __expf(s0[r]*ATT_SCALE);
      float e1 = __expf(s1[r]*ATT_SCALE);
      lsum[r] += e0 + e1;
      Psh[wave][(quad*4+r)*PS + l16     ] = f2bf(e0);
      Psh[wave][(quad*4+r)*PS + l16 + 16] = f2bf(e1);
    }
    // P A-frag + V^T B-frags -> PV
    short8 pf  = *(const short8*)(&Psh[wave][l16*PS + quad*8]);
    short8 vf0 = *(const short8*)(&Vsh[(l16     )*VS + quad*8]);
    short8 vf1 = *(const short8*)(&Vsh[(l16 + 16)*VS + quad*8]);
    o0 = __builtin_amdgcn_mfma_f32_16x16x32_bf16(pf, vf0, o0, 0,0,0);
    o1 = __builtin_amdgcn_mfma_f32_16x16x32_bf16(pf, vf1, o1, 0,0,0);
  }
  // reduce l across the 16-lane group (keys were spread over 16 lanes)
#pragma unroll
  for (int r = 0; r < 4; r++){
    float s = lsum[r];
    s += __shfl_xor(s, 1); s += __shfl_xor(s, 2);
    s += __shfl_xor(s, 4); s += __shfl_xor(s, 8);
    lsum[r] = s;
  }
#pragma unroll
  for (int r = 0; r < 4; r++){
    float inv = 1.f / lsum[r];
    size_t base = (size_t)(b*NN + q0 + quad*4 + r)*CC + hh*HD;
    out[base + l16     ] = f2bf(o0[r]*inv);
    out[base + l16 + 16] = f2bf(o1[r]*inv);
  }
}

// ---------------- h2 = h + dwconv3x3(h) + bias  (hid=1024, h in bf16, w f32) ----------------
__global__ void k_dwh(const bf16u* __restrict__ h, const float* __restrict__ w,
                      const float* __restrict__ bias, bf16u* __restrict__ h2){
  int bn = blockIdx.x;
  int b = bn / NN, n = bn % NN;
  int hy = n / WW, wx = n % WW;
  const bf16u* hb = h + (size_t)b*NN*HIDN;
#pragma unroll
  for (int ci = 0; ci < 4; ci++){
    int c = threadIdx.x + ci*256;
    float acc = bias[c];
#pragma unroll
    for (int kh = 0; kh < 3; kh++){
      int iy = hy + kh - 1; if (iy < 0 || iy >= HH) continue;
#pragma unroll
      for (int kw = 0; kw < 3; kw++){
        int ix = wx + kw - 1; if (ix < 0 || ix >= WW) continue;
        acc += bf2f(hb[(size_t)(iy*WW+ix)*HIDN + c]) * w[c*9 + kh*3 + kw];
      }
    }
    float center = bf2f(hb[(size_t)n*HIDN + c]);
    h2[(size_t)bn*HIDN + c] = f2bf(center + acc);
  }
}

extern "C" void kernel_launch(void* const* d_in, const int* in_sizes, int n_in,
                              void* d_out, int out_size, void* d_ws, size_t ws_size,
                              hipStream_t stream){
  const float* x      = (const float*)d_in[0];
  const float* cpe_w  = (const float*)d_in[1];
  const float* cpe_b  = (const float*)d_in[2];
  const float* n1w    = (const float*)d_in[3];
  const float* n1b    = (const float*)d_in[4];
  const float* q_w    = (const float*)d_in[5];
  const float* kv_w   = (const float*)d_in[6];
  const float* anw    = (const float*)d_in[7];
  const float* anb    = (const float*)d_in[8];
  const float* proj_w = (const float*)d_in[9];
  const float* proj_b = (const float*)d_in[10];
  const float* n2w    = (const float*)d_in[11];
  const float* n2b    = (const float*)d_in[12];
  const float* fc1_w  = (const float*)d_in[13];
  const float* fc1_b  = (const float*)d_in[14];
  const float* irb_w  = (const float*)d_in[15];
  const float* irb_b  = (const float*)d_in[16];
  const float* fc2_w  = (const float*)d_in[17];
  const float* fc2_b  = (const float*)d_in[18];
  const float* dw0    = (const float*)d_in[21];
  const float* db0    = (const float*)d_in[22];
  const float* dw1    = (const float*)d_in[23];
  const float* db1    = (const float*)d_in[24];
  const float* dw2    = (const float*)d_in[25];
  const float* db2    = (const float*)d_in[26];
  const float* dw3    = (const float*)d_in[27];
  const float* db3    = (const float*)d_in[28];

  // workspace: x1 | xn | R
  //   R phase 1 (attention): qb [B*N*C bf16] praw[B*P*C f32] pools[B*P*C f32] kvb[B*P*2C bf16]
  //   R phase 2 (FFN):       hbuf/h2buf overlay praw onward (qb dead after proj)
  float* ws     = (float*)d_ws;
  float* x1     = ws;
  float* xn     = x1     + (size_t)BQ*NN*CC;
  float* R      = xn     + (size_t)BQ*NN*CC;
  bf16u* qb     = (bf16u*)R;                               // B*N*C bf16
  float* praw   = R + (size_t)BQ*NN*CC/2;
  float* pools  = praw   + (size_t)BQ*PP*CC;
  bf16u* kvb    = (bf16u*)(pools + (size_t)BQ*PP*CC);      // B*P*2C bf16
  bf16u* hbuf   = (bf16u*)praw;                            // phase 2 overlay
  bf16u* h2buf  = hbuf + (size_t)BQ*NN*HIDN;

  // 1. CPE + residual
  k_cpe<<<BQ*NN, 256, 0, stream>>>(x, cpe_w, cpe_b, x1);
  // 2. norm1
  k_ln<<<BQ*NN, 256, 0, stream>>>(x1, n1w, n1b, xn);
  // 3. q projection -> bf16
  k_gemm<false,true,false,false,false><<<dim3(CC/64, BQ*NN/64), 256, 0, stream>>>(
      xn, q_w, nullptr, qb, nullptr, BQ*NN, CC, CC);
  // 4. pyramid pooling
  k_pool<<<BQ*PP, 256, 0, stream>>>(xn, praw);
  k_pool_dw<<<BQ*PP, 256, 0, stream>>>(praw, dw0,db0, dw1,db1, dw2,db2, dw3,db3, pools);
  // 5. attn-norm (in-place)
  k_ln<<<BQ*PP, 256, 0, stream>>>(pools, anw, anb, pools);
  // 6. kv projection -> bf16
  k_gemm<false,true,false,false,false><<<dim3(2*CC/64, BQ*PP/64), 256, 0, stream>>>(
      pools, kv_w, nullptr, kvb, nullptr, BQ*PP, 2*CC, CC);
  // 7. MFMA attention (in-place: qb becomes attn output)
  k_attn_mfma<<<BQ*NHEAD*(NN/64), 256, 0, stream>>>(qb, kvb, qb);
  // 8. proj + bias + residual (A bf16; into x1, in-place residual)
  k_gemm<true,false,true,false,true><<<dim3(CC/64, BQ*NN/64), 256, 0, stream>>>(
      qb, proj_w, proj_b, x1, x1, BQ*NN, CC, CC);
  // 9. norm2
  k_ln<<<BQ*NN, 256, 0, stream>>>(x1, n2w, n2b, xn);
  // 10. fc1 + bias + gelu -> h (bf16)
  k_gemm<false,true,true,true,false><<<dim3(HIDN/64, BQ*NN/64), 256, 0, stream>>>(
      xn, fc1_w, fc1_b, hbuf, nullptr, BQ*NN, HIDN, CC);
  // 11. h2 = h + dwconv(h)
  k_dwh<<<BQ*NN, 256, 0, stream>>>(hbuf, irb_w, irb_b, h2buf);
  // 12. fc2 + bias + residual -> d_out (f32)
  k_gemm<true,false,true,false,true><<<dim3(CC/64, BQ*NN/64), 256, 0, stream>>>(
      h2buf, fc2_w, fc2_b, d_out, x1, BQ*NN, CC, HIDN);
}

// Round 5
// 515.288 us; speedup vs baseline: 2.2412x; 1.2914x over previous
//
#include <hip/hip_runtime.h>
#include <hip/hip_bf16.h>

#define BQ 4
#define HH 56
#define WW 56
#define NN (HH*WW)      // 3136
#define CC 256
#define NHEAD 8
#define HD 32
#define PP 1376
#define HIDN 1024
#define EPS_LN 1e-5f
#define ATT_SCALE 0.17677669529663687f

typedef unsigned short bf16u;
typedef __attribute__((ext_vector_type(8))) short short8;
typedef __attribute__((ext_vector_type(4))) float f32x4;

__device__ __forceinline__ float bf2f(bf16u u){
  union { unsigned int i; float f; } v; v.i = ((unsigned int)u) << 16; return v.f;
}
__device__ __forceinline__ bf16u f2bf(float f){
  unsigned int x = __float_as_uint(f);
  x += 0x7fffu + ((x >> 16) & 1u);
  return (bf16u)(x >> 16);
}

// ---------------- CPE: x1 = x + dwconv3x3(x) + bias   (channel-last, f32) ----------------
__global__ void k_cpe(const float* __restrict__ x, const float* __restrict__ w,
                      const float* __restrict__ bias, float* __restrict__ x1){
  int bn = blockIdx.x;
  int b = bn / NN, n = bn % NN;
  int hy = n / WW, wx = n % WW;
  int c = threadIdx.x;
  float wv[9];
#pragma unroll
  for (int k = 0; k < 9; k++) wv[k] = w[c*9+k];
  float acc = bias[c];
  const float* xb = x + (size_t)b*NN*CC + c;
#pragma unroll
  for (int kh = 0; kh < 3; kh++){
    int iy = hy + kh - 1;
    if (iy < 0 || iy >= HH) continue;
#pragma unroll
    for (int kw = 0; kw < 3; kw++){
      int ix = wx + kw - 1;
      if (ix < 0 || ix >= WW) continue;
      acc += xb[(size_t)(iy*WW+ix)*CC] * wv[kh*3+kw];
    }
  }
  float center = xb[(size_t)n*CC];
  x1[(size_t)bn*CC + c] = center + acc;
}

// ---------------- LayerNorm over C=256, one row per block ----------------
__global__ void k_ln(const float* __restrict__ X, const float* __restrict__ g,
                     const float* __restrict__ be, float* Y){
  int row = blockIdx.x;
  int t = threadIdx.x;
  float v = X[(size_t)row*CC + t];
  float s = v, s2 = v*v;
#pragma unroll
  for (int off = 32; off; off >>= 1){
    s  += __shfl_down(s,  off, 64);
    s2 += __shfl_down(s2, off, 64);
  }
  __shared__ float red[10];
  int wv_ = t >> 6, ln = t & 63;
  if (ln == 0){ red[wv_] = s; red[4+wv_] = s2; }
  __syncthreads();
  if (t == 0){
    float S  = red[0]+red[1]+red[2]+red[3];
    float S2 = red[4]+red[5]+red[6]+red[7];
    float mean = S * (1.f/CC);
    float var  = S2 * (1.f/CC) - mean*mean;
    red[8] = mean; red[9] = rsqrtf(var + EPS_LN);
  }
  __syncthreads();
  float mean = red[8], rstd = red[9];
  Y[(size_t)row*CC + t] = (v - mean) * rstd * g[t] + be[t];
}

// ---------------- adaptive avg pool (one (b,p) per block, c = thread) ----------------
__global__ void k_pool(const float* __restrict__ xn, float* __restrict__ praw){
  int bp = blockIdx.x;
  int b = bp / PP, p = bp % PP;
  int ps, pi;
  if (p < 144)      { ps = 12; pi = p; }
  else if (p < 400) { ps = 16; pi = p - 144; }
  else if (p < 800) { ps = 20; pi = p - 400; }
  else              { ps = 24; pi = p - 800; }
  int oi = pi / ps, oj = pi % ps;
  int si = oi*HH/ps, ei = ((oi+1)*HH + ps - 1)/ps;
  int sj = oj*WW/ps, ej = ((oj+1)*WW + ps - 1)/ps;
  int c = threadIdx.x;
  const float* xb = xn + (size_t)b*NN*CC + c;
  float acc = 0.f;
  for (int i = si; i < ei; i++)
    for (int j = sj; j < ej; j++)
      acc += xb[(size_t)(i*WW+j)*CC];
  praw[(size_t)bp*CC + c] = acc / (float)((ei-si)*(ej-sj));
}

// ---------------- pools = praw + dwconv3x3(praw) + bias (per level) ----------------
__global__ void k_pool_dw(const float* __restrict__ praw,
    const float* w0, const float* b0, const float* w1, const float* b1,
    const float* w2, const float* b2, const float* w3, const float* b3,
    float* __restrict__ pools){
  int bp = blockIdx.x;
  int b = bp / PP, p = bp % PP;
  int ps, pi, off; const float *w, *bi;
  if (p < 144)      { ps=12; pi=p;     off=0;   w=w0; bi=b0; }
  else if (p < 400) { ps=16; pi=p-144; off=144; w=w1; bi=b1; }
  else if (p < 800) { ps=20; pi=p-400; off=400; w=w2; bi=b2; }
  else              { ps=24; pi=p-800; off=800; w=w3; bi=b3; }
  int oi = pi/ps, oj = pi%ps;
  int c = threadIdx.x;
  const float* base = praw + (size_t)(b*PP + off)*CC + c;
  float acc = bi[c];
#pragma unroll
  for (int kh = 0; kh < 3; kh++){
    int ii = oi + kh - 1; if (ii < 0 || ii >= ps) continue;
#pragma unroll
    for (int kw = 0; kw < 3; kw++){
      int jj = oj + kw - 1; if (jj < 0 || jj >= ps) continue;
      acc += base[(size_t)(ii*ps+jj)*CC] * w[c*9 + kh*3 + kw];
    }
  }
  float center = base[(size_t)(oi*ps+oj)*CC];
  pools[(size_t)bp*CC + c] = center + acc;
}

// ===== MFMA GEMM: Out[M,Nout] = act(A[M,K] @ Wt[Nout,K]^T + bias) (+Res) =====
// 128x128 tile, 4 waves each 64x64 (4x4 of 16x16x32 bf16 MFMA), BK=32.
// A (f32 or bf16) and Wt (f32) converted to bf16 during LDS staging.
// LDS row stride 40 bf16 (80 B) -> <=2-way bank aliasing (free).
#define GST 40
template<bool TA_BF16, bool OUT_BF16, bool HAS_BIAS, bool DO_GELU, bool HAS_RES>
__global__ __launch_bounds__(256) void k_gemm_mfma(const void* __restrict__ Ap,
                       const float* __restrict__ Wt,
                       const float* __restrict__ bias, void* Outp,
                       const float* Res, int M, int Nout, int K){
  __shared__ bf16u Ash[128*GST];
  __shared__ bf16u Bsh[128*GST];
  int t = threadIdx.x;
  int wave = t >> 6, lane = t & 63, quad = lane >> 4, l16 = lane & 15;
  int m0 = blockIdx.y * 128, n0 = blockIdx.x * 128;
  int wm = (wave >> 1) * 64, wn = (wave & 1) * 64;
  int srow = t >> 1, scol = (t & 1) * 16;
  f32x4 zero = {0.f,0.f,0.f,0.f};
  f32x4 acc[4][4];
#pragma unroll
  for (int i = 0; i < 4; i++)
#pragma unroll
    for (int j = 0; j < 4; j++) acc[i][j] = zero;
  for (int k0 = 0; k0 < K; k0 += 32){
    __syncthreads();
    if constexpr (TA_BF16){
      const bf16u* ap = (const bf16u*)Ap + (size_t)(m0+srow)*K + k0 + scol;
      uint4 u = *(const uint4*)ap;
      uint4 v = *(const uint4*)(ap+8);
      *(uint4*)&Ash[srow*GST + scol]     = u;
      *(uint4*)&Ash[srow*GST + scol + 8] = v;
    } else {
      const float* ap = (const float*)Ap + (size_t)(m0+srow)*K + k0 + scol;
      float4 u0 = *(const float4*)ap,     u1 = *(const float4*)(ap+4);
      float4 u2 = *(const float4*)(ap+8), u3 = *(const float4*)(ap+12);
      ushort4 w0 = {f2bf(u0.x),f2bf(u0.y),f2bf(u0.z),f2bf(u0.w)};
      ushort4 w1 = {f2bf(u1.x),f2bf(u1.y),f2bf(u1.z),f2bf(u1.w)};
      ushort4 w2 = {f2bf(u2.x),f2bf(u2.y),f2bf(u2.z),f2bf(u2.w)};
      ushort4 w3 = {f2bf(u3.x),f2bf(u3.y),f2bf(u3.z),f2bf(u3.w)};
      *(ushort4*)&Ash[srow*GST + scol +  0] = w0;
      *(ushort4*)&Ash[srow*GST + scol +  4] = w1;
      *(ushort4*)&Ash[srow*GST + scol +  8] = w2;
      *(ushort4*)&Ash[srow*GST + scol + 12] = w3;
    }
    {
      const float* bp = Wt + (size_t)(n0+srow)*K + k0 + scol;
      float4 u0 = *(const float4*)bp,     u1 = *(const float4*)(bp+4);
      float4 u2 = *(const float4*)(bp+8), u3 = *(const float4*)(bp+12);
      ushort4 w0 = {f2bf(u0.x),f2bf(u0.y),f2bf(u0.z),f2bf(u0.w)};
      ushort4 w1 = {f2bf(u1.x),f2bf(u1.y),f2bf(u1.z),f2bf(u1.w)};
      ushort4 w2 = {f2bf(u2.x),f2bf(u2.y),f2bf(u2.z),f2bf(u2.w)};
      ushort4 w3 = {f2bf(u3.x),f2bf(u3.y),f2bf(u3.z),f2bf(u3.w)};
      *(ushort4*)&Bsh[srow*GST + scol +  0] = w0;
      *(ushort4*)&Bsh[srow*GST + scol +  4] = w1;
      *(ushort4*)&Bsh[srow*GST + scol +  8] = w2;
      *(ushort4*)&Bsh[srow*GST + scol + 12] = w3;
    }
    __syncthreads();
    short8 af[4], bfr[4];
#pragma unroll
    for (int mi = 0; mi < 4; mi++)
      af[mi] = *(const short8*)&Ash[(wm + mi*16 + l16)*GST + quad*8];
#pragma unroll
    for (int ni = 0; ni < 4; ni++)
      bfr[ni] = *(const short8*)&Bsh[(wn + ni*16 + l16)*GST + quad*8];
#pragma unroll
    for (int mi = 0; mi < 4; mi++)
#pragma unroll
      for (int ni = 0; ni < 4; ni++)
        acc[mi][ni] = __builtin_amdgcn_mfma_f32_16x16x32_bf16(af[mi], bfr[ni], acc[mi][ni], 0,0,0);
  }
  // epilogue: C/D layout row = quad*4+r, col = l16 within each 16x16 block
#pragma unroll
  for (int mi = 0; mi < 4; mi++){
#pragma unroll
    for (int r = 0; r < 4; r++){
      int row = m0 + wm + mi*16 + quad*4 + r;
#pragma unroll
      for (int ni = 0; ni < 4; ni++){
        int col = n0 + wn + ni*16 + l16;
        float v = acc[mi][ni][r];
        if constexpr (HAS_BIAS) v += bias[col];
        if constexpr (DO_GELU)  v = 0.5f*v*(1.f + erff(v*0.70710678118654752f));
        if constexpr (HAS_RES)  v += Res[(size_t)row*Nout + col];
        if constexpr (OUT_BF16) ((bf16u*)Outp)[(size_t)row*Nout + col] = f2bf(v);
        else                    ((float*)Outp)[(size_t)row*Nout + col] = v;
      }
    }
  }
}

// ============ MFMA flash attention ============
#define KS 40
#define VS 40
#define PS 40
__global__ __launch_bounds__(256) void k_attn_mfma(const bf16u* __restrict__ q,
                       const bf16u* __restrict__ kv, bf16u* __restrict__ out){
  __shared__ bf16u Ksh[32*KS];
  __shared__ bf16u Vsh[32*VS];
  __shared__ bf16u Psh[4][16*PS];
  int t = threadIdx.x;
  int wave = t >> 6, lane = t & 63;
  int quad = lane >> 4, l16 = lane & 15;
  int bid = blockIdx.x;
  int qt = bid % (NN/64);
  int hh = (bid / (NN/64)) % NHEAD;
  int b  = bid / ((NN/64)*NHEAD);
  int q0 = qt*64 + wave*16;
  short8 qfrag = *(const short8*)(q + ((size_t)(b*NN + q0 + l16)*CC + hh*HD + quad*8));
  f32x4 zero = {0.f,0.f,0.f,0.f};
  f32x4 o0 = zero, o1 = zero;
  float lsum[4] = {0.f,0.f,0.f,0.f};
  int sp = t & 31, sd0 = (t >> 5) * 4;
  for (int ch = 0; ch < PP/32; ch++){
    int p0 = ch*32;
    __syncthreads();
    {
      const bf16u* src = kv + ((size_t)(b*PP + p0 + sp)*(2*CC) + hh*HD + sd0);
      ushort4 kk = *(const ushort4*)src;
      ushort4 vv = *(const ushort4*)(src + CC);
      *(ushort4*)(&Ksh[sp*KS + sd0]) = kk;
      Vsh[(sd0+0)*VS + sp] = vv.x;
      Vsh[(sd0+1)*VS + sp] = vv.y;
      Vsh[(sd0+2)*VS + sp] = vv.z;
      Vsh[(sd0+3)*VS + sp] = vv.w;
    }
    __syncthreads();
    short8 kf0 = *(const short8*)(&Ksh[(l16     )*KS + quad*8]);
    short8 kf1 = *(const short8*)(&Ksh[(l16 + 16)*KS + quad*8]);
    f32x4 s0 = __builtin_amdgcn_mfma_f32_16x16x32_bf16(qfrag, kf0, zero, 0,0,0);
    f32x4 s1 = __builtin_amdgcn_mfma_f32_16x16x32_bf16(qfrag, kf1, zero, 0,0,0);
#pragma unroll
    for (int r = 0; r < 4; r++){
      float e0 = __expf(s0[r]*ATT_SCALE);
      float e1 = __expf(s1[r]*ATT_SCALE);
      lsum[r] += e0 + e1;
      Psh[wave][(quad*4+r)*PS + l16     ] = f2bf(e0);
      Psh[wave][(quad*4+r)*PS + l16 + 16] = f2bf(e1);
    }
    short8 pf  = *(const short8*)(&Psh[wave][l16*PS + quad*8]);
    short8 vf0 = *(const short8*)(&Vsh[(l16     )*VS + quad*8]);
    short8 vf1 = *(const short8*)(&Vsh[(l16 + 16)*VS + quad*8]);
    o0 = __builtin_amdgcn_mfma_f32_16x16x32_bf16(pf, vf0, o0, 0,0,0);
    o1 = __builtin_amdgcn_mfma_f32_16x16x32_bf16(pf, vf1, o1, 0,0,0);
  }
#pragma unroll
  for (int r = 0; r < 4; r++){
    float s = lsum[r];
    s += __shfl_xor(s, 1); s += __shfl_xor(s, 2);
    s += __shfl_xor(s, 4); s += __shfl_xor(s, 8);
    lsum[r] = s;
  }
#pragma unroll
  for (int r = 0; r < 4; r++){
    float inv = 1.f / lsum[r];
    size_t base = (size_t)(b*NN + q0 + quad*4 + r)*CC + hh*HD;
    out[base + l16     ] = f2bf(o0[r]*inv);
    out[base + l16 + 16] = f2bf(o1[r]*inv);
  }
}

// ---------------- h2 = h + dwconv3x3(h) + bias  (hid=1024, h in bf16, w f32) ----------------
__global__ void k_dwh(const bf16u* __restrict__ h, const float* __restrict__ w,
                      const float* __restrict__ bias, bf16u* __restrict__ h2){
  int bn = blockIdx.x;
  int b = bn / NN, n = bn % NN;
  int hy = n / WW, wx = n % WW;
  const bf16u* hb = h + (size_t)b*NN*HIDN;
#pragma unroll
  for (int ci = 0; ci < 4; ci++){
    int c = threadIdx.x + ci*256;
    float acc = bias[c];
#pragma unroll
    for (int kh = 0; kh < 3; kh++){
      int iy = hy + kh - 1; if (iy < 0 || iy >= HH) continue;
#pragma unroll
      for (int kw = 0; kw < 3; kw++){
        int ix = wx + kw - 1; if (ix < 0 || ix >= WW) continue;
        acc += bf2f(hb[(size_t)(iy*WW+ix)*HIDN + c]) * w[c*9 + kh*3 + kw];
      }
    }
    float center = bf2f(hb[(size_t)n*HIDN + c]);
    h2[(size_t)bn*HIDN + c] = f2bf(center + acc);
  }
}

extern "C" void kernel_launch(void* const* d_in, const int* in_sizes, int n_in,
                              void* d_out, int out_size, void* d_ws, size_t ws_size,
                              hipStream_t stream){
  const float* x      = (const float*)d_in[0];
  const float* cpe_w  = (const float*)d_in[1];
  const float* cpe_b  = (const float*)d_in[2];
  const float* n1w    = (const float*)d_in[3];
  const float* n1b    = (const float*)d_in[4];
  const float* q_w    = (const float*)d_in[5];
  const float* kv_w   = (const float*)d_in[6];
  const float* anw    = (const float*)d_in[7];
  const float* anb    = (const float*)d_in[8];
  const float* proj_w = (const float*)d_in[9];
  const float* proj_b = (const float*)d_in[10];
  const float* n2w    = (const float*)d_in[11];
  const float* n2b    = (const float*)d_in[12];
  const float* fc1_w  = (const float*)d_in[13];
  const float* fc1_b  = (const float*)d_in[14];
  const float* irb_w  = (const float*)d_in[15];
  const float* irb_b  = (const float*)d_in[16];
  const float* fc2_w  = (const float*)d_in[17];
  const float* fc2_b  = (const float*)d_in[18];
  const float* dw0    = (const float*)d_in[21];
  const float* db0    = (const float*)d_in[22];
  const float* dw1    = (const float*)d_in[23];
  const float* db1    = (const float*)d_in[24];
  const float* dw2    = (const float*)d_in[25];
  const float* db2    = (const float*)d_in[26];
  const float* dw3    = (const float*)d_in[27];
  const float* db3    = (const float*)d_in[28];

  // workspace: x1 | xn | R
  //   R phase 1 (attention): qb [B*N*C bf16] praw[B*P*C f32] pools[B*P*C f32] kvb[B*P*2C bf16]
  //   R phase 2 (FFN):       hbuf/h2buf overlay praw onward (qb dead after proj)
  float* ws     = (float*)d_ws;
  float* x1     = ws;
  float* xn     = x1     + (size_t)BQ*NN*CC;
  float* R      = xn     + (size_t)BQ*NN*CC;
  bf16u* qb     = (bf16u*)R;
  float* praw   = R + (size_t)BQ*NN*CC/2;
  float* pools  = praw   + (size_t)BQ*PP*CC;
  bf16u* kvb    = (bf16u*)(pools + (size_t)BQ*PP*CC);
  bf16u* hbuf   = (bf16u*)praw;
  bf16u* h2buf  = hbuf + (size_t)BQ*NN*HIDN;

  // 1. CPE + residual
  k_cpe<<<BQ*NN, 256, 0, stream>>>(x, cpe_w, cpe_b, x1);
  // 2. norm1
  k_ln<<<BQ*NN, 256, 0, stream>>>(x1, n1w, n1b, xn);
  // 3. q projection -> bf16 (MFMA)
  k_gemm_mfma<false,true,false,false,false><<<dim3(CC/128, BQ*NN/128), 256, 0, stream>>>(
      xn, q_w, nullptr, qb, nullptr, BQ*NN, CC, CC);
  // 4. pyramid pooling
  k_pool<<<BQ*PP, 256, 0, stream>>>(xn, praw);
  k_pool_dw<<<BQ*PP, 256, 0, stream>>>(praw, dw0,db0, dw1,db1, dw2,db2, dw3,db3, pools);
  // 5. attn-norm (in-place)
  k_ln<<<BQ*PP, 256, 0, stream>>>(pools, anw, anb, pools);
  // 6. kv projection -> bf16 (MFMA)
  k_gemm_mfma<false,true,false,false,false><<<dim3(2*CC/128, BQ*PP/128), 256, 0, stream>>>(
      pools, kv_w, nullptr, kvb, nullptr, BQ*PP, 2*CC, CC);
  // 7. MFMA attention (in-place: qb becomes attn output)
  k_attn_mfma<<<BQ*NHEAD*(NN/64), 256, 0, stream>>>(qb, kvb, qb);
  // 8. proj + bias + residual (A bf16; into x1, in-place residual) (MFMA)
  k_gemm_mfma<true,false,true,false,true><<<dim3(CC/128, BQ*NN/128), 256, 0, stream>>>(
      qb, proj_w, proj_b, x1, x1, BQ*NN, CC, CC);
  // 9. norm2
  k_ln<<<BQ*NN, 256, 0, stream>>>(x1, n2w, n2b, xn);
  // 10. fc1 + bias + gelu -> h (bf16) (MFMA)
  k_gemm_mfma<false,true,true,true,false><<<dim3(HIDN/128, BQ*NN/128), 256, 0, stream>>>(
      xn, fc1_w, fc1_b, hbuf, nullptr, BQ*NN, HIDN, CC);
  // 11. h2 = h + dwconv(h)
  k_dwh<<<BQ*NN, 256, 0, stream>>>(hbuf, irb_w, irb_b, h2buf);
  // 12. fc2 + bias + residual -> d_out (f32) (MFMA)
  k_gemm_mfma<true,false,true,false,true><<<dim3(CC/128, BQ*NN/128), 256, 0, stream>>>(
      h2buf, fc2_w, fc2_b, d_out, x1, BQ*NN, CC, HIDN);
}

// Round 6
// 463.256 us; speedup vs baseline: 2.4929x; 1.1123x over previous
//
#include <hip/hip_runtime.h>
#include <hip/hip_bf16.h>

#define BQ 4
#define HH 56
#define WW 56
#define NN (HH*WW)      // 3136
#define CC 256
#define NHEAD 8
#define HD 32
#define PP 1376
#define HIDN 1024
#define EPS_LN 1e-5f
#define ATT_SCALE 0.17677669529663687f

typedef unsigned short bf16u;
typedef __attribute__((ext_vector_type(8))) short short8;
typedef __attribute__((ext_vector_type(4))) float f32x4;

__device__ __forceinline__ float bf2f(bf16u u){
  union { unsigned int i; float f; } v; v.i = ((unsigned int)u) << 16; return v.f;
}
__device__ __forceinline__ bf16u f2bf(float f){
  unsigned int x = __float_as_uint(f);
  x += 0x7fffu + ((x >> 16) & 1u);
  return (bf16u)(x >> 16);
}

// ---------------- CPE: x1 = x + dwconv3x3(x) + bias (channel-last, f32) ----------------
// 4 pixels/block, 64 threads x 4ch (float4) each
__global__ void k_cpe(const float* __restrict__ x, const float* __restrict__ w,
                      const float* __restrict__ bias, float* __restrict__ x1){
  int t = threadIdx.x;
  int pix = blockIdx.x*4 + (t >> 6);
  int b = pix / NN, n = pix % NN;
  int hy = n / WW, wx = n % WW;
  int c0 = (t & 63) * 4;
  float wv[4][9];
  float acc[4];
#pragma unroll
  for (int cc = 0; cc < 4; cc++){
    acc[cc] = bias[c0+cc];
#pragma unroll
    for (int k = 0; k < 9; k++) wv[cc][k] = w[(c0+cc)*9 + k];
  }
  const float* xb = x + (size_t)b*NN*CC + c0;
#pragma unroll
  for (int kh = 0; kh < 3; kh++){
    int iy = hy + kh - 1;
    if (iy < 0 || iy >= HH) continue;
#pragma unroll
    for (int kw = 0; kw < 3; kw++){
      int ix = wx + kw - 1;
      if (ix < 0 || ix >= WW) continue;
      float4 v = *(const float4*)&xb[(size_t)(iy*WW+ix)*CC];
      int k = kh*3+kw;
      acc[0] += v.x*wv[0][k]; acc[1] += v.y*wv[1][k];
      acc[2] += v.z*wv[2][k]; acc[3] += v.w*wv[3][k];
    }
  }
  float4 cv = *(const float4*)&xb[(size_t)n*CC];
  float4 o;
  o.x = cv.x + acc[0]; o.y = cv.y + acc[1];
  o.z = cv.z + acc[2]; o.w = cv.w + acc[3];
  *(float4*)&x1[(size_t)pix*CC + c0] = o;
}

// ---------------- LayerNorm over C=256, one row per block ----------------
__global__ void k_ln(const float* __restrict__ X, const float* __restrict__ g,
                     const float* __restrict__ be, float* Y){
  int row = blockIdx.x;
  int t = threadIdx.x;
  float v = X[(size_t)row*CC + t];
  float s = v, s2 = v*v;
#pragma unroll
  for (int off = 32; off; off >>= 1){
    s  += __shfl_down(s,  off, 64);
    s2 += __shfl_down(s2, off, 64);
  }
  __shared__ float red[10];
  int wv_ = t >> 6, ln = t & 63;
  if (ln == 0){ red[wv_] = s; red[4+wv_] = s2; }
  __syncthreads();
  if (t == 0){
    float S  = red[0]+red[1]+red[2]+red[3];
    float S2 = red[4]+red[5]+red[6]+red[7];
    float mean = S * (1.f/CC);
    float var  = S2 * (1.f/CC) - mean*mean;
    red[8] = mean; red[9] = rsqrtf(var + EPS_LN);
  }
  __syncthreads();
  float mean = red[8], rstd = red[9];
  Y[(size_t)row*CC + t] = (v - mean) * rstd * g[t] + be[t];
}

// ---------------- adaptive avg pool (one (b,p) per block, c = thread) ----------------
__global__ void k_pool(const float* __restrict__ xn, float* __restrict__ praw){
  int bp = blockIdx.x;
  int b = bp / PP, p = bp % PP;
  int ps, pi;
  if (p < 144)      { ps = 12; pi = p; }
  else if (p < 400) { ps = 16; pi = p - 144; }
  else if (p < 800) { ps = 20; pi = p - 400; }
  else              { ps = 24; pi = p - 800; }
  int oi = pi / ps, oj = pi % ps;
  int si = oi*HH/ps, ei = ((oi+1)*HH + ps - 1)/ps;
  int sj = oj*WW/ps, ej = ((oj+1)*WW + ps - 1)/ps;
  int c = threadIdx.x;
  const float* xb = xn + (size_t)b*NN*CC + c;
  float acc = 0.f;
  for (int i = si; i < ei; i++)
    for (int j = sj; j < ej; j++)
      acc += xb[(size_t)(i*WW+j)*CC];
  praw[(size_t)bp*CC + c] = acc / (float)((ei-si)*(ej-sj));
}

// ---------------- pools = praw + dwconv3x3(praw) + bias (per level) ----------------
__global__ void k_pool_dw(const float* __restrict__ praw,
    const float* w0, const float* b0, const float* w1, const float* b1,
    const float* w2, const float* b2, const float* w3, const float* b3,
    float* __restrict__ pools){
  int bp = blockIdx.x;
  int b = bp / PP, p = bp % PP;
  int ps, pi, off; const float *w, *bi;
  if (p < 144)      { ps=12; pi=p;     off=0;   w=w0; bi=b0; }
  else if (p < 400) { ps=16; pi=p-144; off=144; w=w1; bi=b1; }
  else if (p < 800) { ps=20; pi=p-400; off=400; w=w2; bi=b2; }
  else              { ps=24; pi=p-800; off=800; w=w3; bi=b3; }
  int oi = pi/ps, oj = pi%ps;
  int c = threadIdx.x;
  const float* base = praw + (size_t)(b*PP + off)*CC + c;
  float acc = bi[c];
#pragma unroll
  for (int kh = 0; kh < 3; kh++){
    int ii = oi + kh - 1; if (ii < 0 || ii >= ps) continue;
#pragma unroll
    for (int kw = 0; kw < 3; kw++){
      int jj = oj + kw - 1; if (jj < 0 || jj >= ps) continue;
      acc += base[(size_t)(ii*ps+jj)*CC] * w[c*9 + kh*3 + kw];
    }
  }
  float center = base[(size_t)(oi*ps+oj)*CC];
  pools[(size_t)bp*CC + c] = center + acc;
}

// ===== MFMA GEMM: Out[M,Nout] = act(A[M,K] @ Wt[Nout,K]^T + bias) (+Res) =====
#define GST 40
template<bool TA_BF16, bool OUT_BF16, bool HAS_BIAS, bool DO_GELU, bool HAS_RES>
__global__ __launch_bounds__(256) void k_gemm_mfma(const void* __restrict__ Ap,
                       const float* __restrict__ Wt,
                       const float* __restrict__ bias, void* Outp,
                       const float* Res, int M, int Nout, int K){
  __shared__ bf16u Ash[128*GST];
  __shared__ bf16u Bsh[128*GST];
  int t = threadIdx.x;
  int wave = t >> 6, lane = t & 63, quad = lane >> 4, l16 = lane & 15;
  int m0 = blockIdx.y * 128, n0 = blockIdx.x * 128;
  int wm = (wave >> 1) * 64, wn = (wave & 1) * 64;
  int srow = t >> 1, scol = (t & 1) * 16;
  f32x4 zero = {0.f,0.f,0.f,0.f};
  f32x4 acc[4][4];
#pragma unroll
  for (int i = 0; i < 4; i++)
#pragma unroll
    for (int j = 0; j < 4; j++) acc[i][j] = zero;
  for (int k0 = 0; k0 < K; k0 += 32){
    __syncthreads();
    if constexpr (TA_BF16){
      const bf16u* ap = (const bf16u*)Ap + (size_t)(m0+srow)*K + k0 + scol;
      uint4 u = *(const uint4*)ap;
      uint4 v = *(const uint4*)(ap+8);
      *(uint4*)&Ash[srow*GST + scol]     = u;
      *(uint4*)&Ash[srow*GST + scol + 8] = v;
    } else {
      const float* ap = (const float*)Ap + (size_t)(m0+srow)*K + k0 + scol;
      float4 u0 = *(const float4*)ap,     u1 = *(const float4*)(ap+4);
      float4 u2 = *(const float4*)(ap+8), u3 = *(const float4*)(ap+12);
      ushort4 w0 = {f2bf(u0.x),f2bf(u0.y),f2bf(u0.z),f2bf(u0.w)};
      ushort4 w1 = {f2bf(u1.x),f2bf(u1.y),f2bf(u1.z),f2bf(u1.w)};
      ushort4 w2 = {f2bf(u2.x),f2bf(u2.y),f2bf(u2.z),f2bf(u2.w)};
      ushort4 w3 = {f2bf(u3.x),f2bf(u3.y),f2bf(u3.z),f2bf(u3.w)};
      *(ushort4*)&Ash[srow*GST + scol +  0] = w0;
      *(ushort4*)&Ash[srow*GST + scol +  4] = w1;
      *(ushort4*)&Ash[srow*GST + scol +  8] = w2;
      *(ushort4*)&Ash[srow*GST + scol + 12] = w3;
    }
    {
      const float* bp = Wt + (size_t)(n0+srow)*K + k0 + scol;
      float4 u0 = *(const float4*)bp,     u1 = *(const float4*)(bp+4);
      float4 u2 = *(const float4*)(bp+8), u3 = *(const float4*)(bp+12);
      ushort4 w0 = {f2bf(u0.x),f2bf(u0.y),f2bf(u0.z),f2bf(u0.w)};
      ushort4 w1 = {f2bf(u1.x),f2bf(u1.y),f2bf(u1.z),f2bf(u1.w)};
      ushort4 w2 = {f2bf(u2.x),f2bf(u2.y),f2bf(u2.z),f2bf(u2.w)};
      ushort4 w3 = {f2bf(u3.x),f2bf(u3.y),f2bf(u3.z),f2bf(u3.w)};
      *(ushort4*)&Bsh[srow*GST + scol +  0] = w0;
      *(ushort4*)&Bsh[srow*GST + scol +  4] = w1;
      *(ushort4*)&Bsh[srow*GST + scol +  8] = w2;
      *(ushort4*)&Bsh[srow*GST + scol + 12] = w3;
    }
    __syncthreads();
    short8 af[4], bfr[4];
#pragma unroll
    for (int mi = 0; mi < 4; mi++)
      af[mi] = *(const short8*)&Ash[(wm + mi*16 + l16)*GST + quad*8];
#pragma unroll
    for (int ni = 0; ni < 4; ni++)
      bfr[ni] = *(const short8*)&Bsh[(wn + ni*16 + l16)*GST + quad*8];
#pragma unroll
    for (int mi = 0; mi < 4; mi++)
#pragma unroll
      for (int ni = 0; ni < 4; ni++)
        acc[mi][ni] = __builtin_amdgcn_mfma_f32_16x16x32_bf16(af[mi], bfr[ni], acc[mi][ni], 0,0,0);
  }
#pragma unroll
  for (int mi = 0; mi < 4; mi++){
#pragma unroll
    for (int r = 0; r < 4; r++){
      int row = m0 + wm + mi*16 + quad*4 + r;
#pragma unroll
      for (int ni = 0; ni < 4; ni++){
        int col = n0 + wn + ni*16 + l16;
        float v = acc[mi][ni][r];
        if constexpr (HAS_BIAS) v += bias[col];
        if constexpr (DO_GELU)  v = 0.5f*v*(1.f + erff(v*0.70710678118654752f));
        if constexpr (HAS_RES)  v += Res[(size_t)row*Nout + col];
        if constexpr (OUT_BF16) ((bf16u*)Outp)[(size_t)row*Nout + col] = f2bf(v);
        else                    ((float*)Outp)[(size_t)row*Nout + col] = v;
      }
    }
  }
}

// ============ MFMA flash attention: 64 q x 2 heads per block ============
// Heads hp*2, hp*2+1 are adjacent 32-dim slices -> K/V staging is one contiguous
// 64-dim load. 32-key chunks; next chunk's global loads prefetched into regs
// before the barrier. 8 MFMA per wave per chunk. No max-subtraction (|s|<~4).
#define KST 72   // rows 144B: 16B-aligned, frag reads 2-way banks (free)
#define VST 72
#define PST 72
__global__ __launch_bounds__(256) void k_attn_mfma(const bf16u* __restrict__ q,
                       const bf16u* __restrict__ kv, bf16u* __restrict__ out){
  __shared__ bf16u Ksh[32*KST];     // [key][64 dims (2 heads)]
  __shared__ bf16u Vsh[64*VST];     // [dim][key] (transposed)
  __shared__ bf16u Psh[8][16*PST];  // [wave*2+h][query][key]
  int t = threadIdx.x;
  int wave = t >> 6, lane = t & 63, quad = lane >> 4, l16 = lane & 15;
  int bid = blockIdx.x;
  int qt = bid % (NN/64);
  int hp = (bid / (NN/64)) % (NHEAD/2);
  int b  = bid / ((NN/64)*(NHEAD/2));
  int q0 = qt*64 + wave*16;
  const bf16u* qb = q + (size_t)(b*NN + q0 + l16)*CC + hp*64 + quad*8;
  short8 qf0 = *(const short8*)qb;
  short8 qf1 = *(const short8*)(qb + HD);
  f32x4 zero = {0.f,0.f,0.f,0.f};
  f32x4 o00 = zero, o01 = zero, o10 = zero, o11 = zero;
  float ls0[4] = {0.f,0.f,0.f,0.f}, ls1[4] = {0.f,0.f,0.f,0.f};
  int sp = t & 31, sd0 = (t >> 5) * 8;
  const bf16u* kvp = kv + (size_t)(b*PP + sp)*(2*CC) + hp*64 + sd0;
  uint4 kk = *(const uint4*)kvp;
  uint4 vv = *(const uint4*)(kvp + CC);
  for (int ch = 0; ch < PP/32; ch++){
    __syncthreads();                       // prev compute done reading LDS
    *(uint4*)&Ksh[sp*KST + sd0] = kk;
    Vsh[(sd0+0)*VST + sp] = (bf16u)(vv.x & 0xffff);
    Vsh[(sd0+1)*VST + sp] = (bf16u)(vv.x >> 16);
    Vsh[(sd0+2)*VST + sp] = (bf16u)(vv.y & 0xffff);
    Vsh[(sd0+3)*VST + sp] = (bf16u)(vv.y >> 16);
    Vsh[(sd0+4)*VST + sp] = (bf16u)(vv.z & 0xffff);
    Vsh[(sd0+5)*VST + sp] = (bf16u)(vv.z >> 16);
    Vsh[(sd0+6)*VST + sp] = (bf16u)(vv.w & 0xffff);
    Vsh[(sd0+7)*VST + sp] = (bf16u)(vv.w >> 16);
    if (ch < PP/32 - 1){                   // prefetch next chunk (overlaps compute)
      kvp += 32*2*CC;
      kk = *(const uint4*)kvp;
      vv = *(const uint4*)(kvp + CC);
    }
    __syncthreads();
    short8 kf00 = *(const short8*)&Ksh[(l16     )*KST +      quad*8];
    short8 kf01 = *(const short8*)&Ksh[(l16 + 16)*KST +      quad*8];
    short8 kf10 = *(const short8*)&Ksh[(l16     )*KST + 32 + quad*8];
    short8 kf11 = *(const short8*)&Ksh[(l16 + 16)*KST + 32 + quad*8];
    f32x4 s00 = __builtin_amdgcn_mfma_f32_16x16x32_bf16(qf0, kf00, zero, 0,0,0);
    f32x4 s01 = __builtin_amdgcn_mfma_f32_16x16x32_bf16(qf0, kf01, zero, 0,0,0);
    f32x4 s10 = __builtin_amdgcn_mfma_f32_16x16x32_bf16(qf1, kf10, zero, 0,0,0);
    f32x4 s11 = __builtin_amdgcn_mfma_f32_16x16x32_bf16(qf1, kf11, zero, 0,0,0);
    bf16u* P0 = &Psh[wave*2+0][0];
    bf16u* P1 = &Psh[wave*2+1][0];
#pragma unroll
    for (int r = 0; r < 4; r++){
      float e00 = __expf(s00[r]*ATT_SCALE), e01 = __expf(s01[r]*ATT_SCALE);
      float e10 = __expf(s10[r]*ATT_SCALE), e11 = __expf(s11[r]*ATT_SCALE);
      ls0[r] += e00 + e01; ls1[r] += e10 + e11;
      P0[(quad*4+r)*PST + l16     ] = f2bf(e00);
      P0[(quad*4+r)*PST + l16 + 16] = f2bf(e01);
      P1[(quad*4+r)*PST + l16     ] = f2bf(e10);
      P1[(quad*4+r)*PST + l16 + 16] = f2bf(e11);
    }
    short8 pf0 = *(const short8*)&P0[l16*PST + quad*8];
    short8 pf1 = *(const short8*)&P1[l16*PST + quad*8];
    short8 vf00 = *(const short8*)&Vsh[(     l16)*VST + quad*8];
    short8 vf01 = *(const short8*)&Vsh[(16 + l16)*VST + quad*8];
    short8 vf10 = *(const short8*)&Vsh[(32 + l16)*VST + quad*8];
    short8 vf11 = *(const short8*)&Vsh[(48 + l16)*VST + quad*8];
    o00 = __builtin_amdgcn_mfma_f32_16x16x32_bf16(pf0, vf00, o00, 0,0,0);
    o01 = __builtin_amdgcn_mfma_f32_16x16x32_bf16(pf0, vf01, o01, 0,0,0);
    o10 = __builtin_amdgcn_mfma_f32_16x16x32_bf16(pf1, vf10, o10, 0,0,0);
    o11 = __builtin_amdgcn_mfma_f32_16x16x32_bf16(pf1, vf11, o11, 0,0,0);
  }
#pragma unroll
  for (int r = 0; r < 4; r++){
    float s0 = ls0[r], s1 = ls1[r];
    s0 += __shfl_xor(s0,1); s0 += __shfl_xor(s0,2);
    s0 += __shfl_xor(s0,4); s0 += __shfl_xor(s0,8);
    s1 += __shfl_xor(s1,1); s1 += __shfl_xor(s1,2);
    s1 += __shfl_xor(s1,4); s1 += __shfl_xor(s1,8);
    ls0[r] = s0; ls1[r] = s1;
  }
#pragma unroll
  for (int r = 0; r < 4; r++){
    size_t base = (size_t)(b*NN + q0 + quad*4 + r)*CC + hp*64;
    float i0 = 1.f/ls0[r], i1 = 1.f/ls1[r];
    out[base + l16     ] = f2bf(o00[r]*i0);
    out[base + 16 + l16] = f2bf(o01[r]*i0);
    out[base + 32 + l16] = f2bf(o10[r]*i1);
    out[base + 48 + l16] = f2bf(o11[r]*i1);
  }
}

// ---------------- h2 = h + dwconv3x3(h) + bias  (hid=1024, bf16, vectorized) ----------------
// 1 pixel/block, 256 threads x 4ch (ushort4 = 8B loads)
__global__ void k_dwh(const bf16u* __restrict__ h, const float* __restrict__ w,
                      const float* __restrict__ bias, bf16u* __restrict__ h2){
  int pix = blockIdx.x;
  int b = pix / NN, n = pix % NN;
  int hy = n / WW, wx = n % WW;
  int c0 = threadIdx.x * 4;
  float wv[4][9];
  float acc[4];
#pragma unroll
  for (int cc = 0; cc < 4; cc++){
    acc[cc] = bias[c0+cc];
#pragma unroll
    for (int k = 0; k < 9; k++) wv[cc][k] = w[(c0+cc)*9 + k];
  }
  const bf16u* hb = h + (size_t)b*NN*HIDN + c0;
#pragma unroll
  for (int kh = 0; kh < 3; kh++){
    int iy = hy + kh - 1; if (iy < 0 || iy >= HH) continue;
#pragma unroll
    for (int kw = 0; kw < 3; kw++){
      int ix = wx + kw - 1; if (ix < 0 || ix >= WW) continue;
      ushort4 hv = *(const ushort4*)&hb[(size_t)(iy*WW+ix)*HIDN];
      int k = kh*3+kw;
      acc[0] += bf2f(hv.x)*wv[0][k]; acc[1] += bf2f(hv.y)*wv[1][k];
      acc[2] += bf2f(hv.z)*wv[2][k]; acc[3] += bf2f(hv.w)*wv[3][k];
    }
  }
  ushort4 cv = *(const ushort4*)&hb[(size_t)n*HIDN];
  ushort4 o;
  o.x = f2bf(bf2f(cv.x) + acc[0]); o.y = f2bf(bf2f(cv.y) + acc[1]);
  o.z = f2bf(bf2f(cv.z) + acc[2]); o.w = f2bf(bf2f(cv.w) + acc[3]);
  *(ushort4*)&h2[(size_t)pix*HIDN + c0] = o;
}

extern "C" void kernel_launch(void* const* d_in, const int* in_sizes, int n_in,
                              void* d_out, int out_size, void* d_ws, size_t ws_size,
                              hipStream_t stream){
  const float* x      = (const float*)d_in[0];
  const float* cpe_w  = (const float*)d_in[1];
  const float* cpe_b  = (const float*)d_in[2];
  const float* n1w    = (const float*)d_in[3];
  const float* n1b    = (const float*)d_in[4];
  const float* q_w    = (const float*)d_in[5];
  const float* kv_w   = (const float*)d_in[6];
  const float* anw    = (const float*)d_in[7];
  const float* anb    = (const float*)d_in[8];
  const float* proj_w = (const float*)d_in[9];
  const float* proj_b = (const float*)d_in[10];
  const float* n2w    = (const float*)d_in[11];
  const float* n2b    = (const float*)d_in[12];
  const float* fc1_w  = (const float*)d_in[13];
  const float* fc1_b  = (const float*)d_in[14];
  const float* irb_w  = (const float*)d_in[15];
  const float* irb_b  = (const float*)d_in[16];
  const float* fc2_w  = (const float*)d_in[17];
  const float* fc2_b  = (const float*)d_in[18];
  const float* dw0    = (const float*)d_in[21];
  const float* db0    = (const float*)d_in[22];
  const float* dw1    = (const float*)d_in[23];
  const float* db1    = (const float*)d_in[24];
  const float* dw2    = (const float*)d_in[25];
  const float* db2    = (const float*)d_in[26];
  const float* dw3    = (const float*)d_in[27];
  const float* db3    = (const float*)d_in[28];

  float* ws     = (float*)d_ws;
  float* x1     = ws;
  float* xn     = x1     + (size_t)BQ*NN*CC;
  float* R      = xn     + (size_t)BQ*NN*CC;
  bf16u* qb     = (bf16u*)R;
  float* praw   = R + (size_t)BQ*NN*CC/2;
  float* pools  = praw   + (size_t)BQ*PP*CC;
  bf16u* kvb    = (bf16u*)(pools + (size_t)BQ*PP*CC);
  bf16u* hbuf   = (bf16u*)praw;
  bf16u* h2buf  = hbuf + (size_t)BQ*NN*HIDN;

  // 1. CPE + residual
  k_cpe<<<BQ*NN/4, 256, 0, stream>>>(x, cpe_w, cpe_b, x1);
  // 2. norm1
  k_ln<<<BQ*NN, 256, 0, stream>>>(x1, n1w, n1b, xn);
  // 3. q projection -> bf16 (MFMA)
  k_gemm_mfma<false,true,false,false,false><<<dim3(CC/128, BQ*NN/128), 256, 0, stream>>>(
      xn, q_w, nullptr, qb, nullptr, BQ*NN, CC, CC);
  // 4. pyramid pooling
  k_pool<<<BQ*PP, 256, 0, stream>>>(xn, praw);
  k_pool_dw<<<BQ*PP, 256, 0, stream>>>(praw, dw0,db0, dw1,db1, dw2,db2, dw3,db3, pools);
  // 5. attn-norm (in-place)
  k_ln<<<BQ*PP, 256, 0, stream>>>(pools, anw, anb, pools);
  // 6. kv projection -> bf16 (MFMA)
  k_gemm_mfma<false,true,false,false,false><<<dim3(2*CC/128, BQ*PP/128), 256, 0, stream>>>(
      pools, kv_w, nullptr, kvb, nullptr, BQ*PP, 2*CC, CC);
  // 7. MFMA attention, 2 heads/block (in-place: qb becomes attn output)
  k_attn_mfma<<<BQ*(NHEAD/2)*(NN/64), 256, 0, stream>>>(qb, kvb, qb);
  // 8. proj + bias + residual (A bf16; into x1) (MFMA)
  k_gemm_mfma<true,false,true,false,true><<<dim3(CC/128, BQ*NN/128), 256, 0, stream>>>(
      qb, proj_w, proj_b, x1, x1, BQ*NN, CC, CC);
  // 9. norm2
  k_ln<<<BQ*NN, 256, 0, stream>>>(x1, n2w, n2b, xn);
  // 10. fc1 + bias + gelu -> h (bf16) (MFMA)
  k_gemm_mfma<false,true,true,true,false><<<dim3(HIDN/128, BQ*NN/128), 256, 0, stream>>>(
      xn, fc1_w, fc1_b, hbuf, nullptr, BQ*NN, HIDN, CC);
  // 11. h2 = h + dwconv(h)  (vectorized)
  k_dwh<<<BQ*NN, 256, 0, stream>>>(hbuf, irb_w, irb_b, h2buf);
  // 12. fc2 + bias + residual -> d_out (f32) (MFMA)
  k_gemm_mfma<true,false,true,false,true><<<dim3(CC/128, BQ*NN/128), 256, 0, stream>>>(
      h2buf, fc2_w, fc2_b, d_out, x1, BQ*NN, CC, HIDN);
}

// Round 7
// 432.431 us; speedup vs baseline: 2.6706x; 1.0713x over previous
//
#include <hip/hip_runtime.h>
#include <hip/hip_bf16.h>

#define BQ 4
#define HH 56
#define WW 56
#define NN (HH*WW)      // 3136
#define CC 256
#define NHEAD 8
#define HD 32
#define PP 1376
#define HIDN 1024
#define EPS_LN 1e-5f
// ATT_SCALE * log2(e): scores from QK^T come out ready for exp2
#define QSCALE_LOG2E 0.25503484f

typedef unsigned short bf16u;
typedef __attribute__((ext_vector_type(8))) short short8;
typedef __attribute__((ext_vector_type(4))) float f32x4;

__device__ __forceinline__ float bf2f(bf16u u){
  union { unsigned int i; float f; } v; v.i = ((unsigned int)u) << 16; return v.f;
}
// RTNE (used in once-per-launch weight convert)
__device__ __forceinline__ bf16u f2bf(float f){
  unsigned int x = __float_as_uint(f);
  x += 0x7fffu + ((x >> 16) & 1u);
  return (bf16u)(x >> 16);
}
// cheap half-up round (2 ops) for hot paths
__device__ __forceinline__ bf16u f2bf_r(float f){
  return (bf16u)((__float_as_uint(f) + 0x8000u) >> 16);
}

// ---------------- weights -> bf16, once per launch ----------------
// segments (elems): q 65536 | kv 131072 | proj 65536 | fc1 262144 | fc2 262144
__global__ void k_wconv(const float* __restrict__ qw, const float* __restrict__ kvw,
                        const float* __restrict__ pw, const float* __restrict__ f1,
                        const float* __restrict__ f2, bf16u* __restrict__ o){
  int off = (blockIdx.x*256 + threadIdx.x) * 4;
  const float* s;
  if (off < 65536)       s = qw  + off;
  else if (off < 196608) s = kvw + off - 65536;
  else if (off < 262144) s = pw  + off - 196608;
  else if (off < 524288) s = f1  + off - 262144;
  else                   s = f2  + off - 524288;
  float4 v = *(const float4*)s;
  ushort4 u = {f2bf(v.x), f2bf(v.y), f2bf(v.z), f2bf(v.w)};
  *(ushort4*)(o + off) = u;
}

// ---------------- CPE + norm1 fused: x1 = x + dwconv(x)+b; xn/xnb = LN(x1) ----------------
// 4 pixels/block, one wave per pixel (64 lanes x 4ch) -> LN is a wave shuffle reduce
__global__ void k_cpe_ln(const float* __restrict__ x, const float* __restrict__ w,
                         const float* __restrict__ bias, const float* __restrict__ g,
                         const float* __restrict__ be, float* __restrict__ x1,
                         float* __restrict__ xn, bf16u* __restrict__ xnb){
  int t = threadIdx.x;
  int pix = blockIdx.x*4 + (t >> 6);
  int b = pix / NN, n = pix % NN;
  int hy = n / WW, wx = n % WW;
  int c0 = (t & 63) * 4;
  float wv[4][9];
  float acc[4];
#pragma unroll
  for (int cc = 0; cc < 4; cc++){
    acc[cc] = bias[c0+cc];
#pragma unroll
    for (int k = 0; k < 9; k++) wv[cc][k] = w[(c0+cc)*9 + k];
  }
  const float* xb = x + (size_t)b*NN*CC + c0;
#pragma unroll
  for (int kh = 0; kh < 3; kh++){
    int iy = hy + kh - 1;
    if (iy < 0 || iy >= HH) continue;
#pragma unroll
    for (int kw = 0; kw < 3; kw++){
      int ix = wx + kw - 1;
      if (ix < 0 || ix >= WW) continue;
      float4 v = *(const float4*)&xb[(size_t)(iy*WW+ix)*CC];
      int k = kh*3+kw;
      acc[0] += v.x*wv[0][k]; acc[1] += v.y*wv[1][k];
      acc[2] += v.z*wv[2][k]; acc[3] += v.w*wv[3][k];
    }
  }
  float4 cv = *(const float4*)&xb[(size_t)n*CC];
  float o0 = cv.x + acc[0], o1 = cv.y + acc[1];
  float o2 = cv.z + acc[2], o3 = cv.w + acc[3];
  float4 ov = {o0,o1,o2,o3};
  *(float4*)&x1[(size_t)pix*CC + c0] = ov;
  // wave LN
  float s  = o0+o1+o2+o3;
  float s2 = o0*o0+o1*o1+o2*o2+o3*o3;
#pragma unroll
  for (int off = 32; off; off >>= 1){
    s  += __shfl_xor(s,  off);
    s2 += __shfl_xor(s2, off);
  }
  float mean = s * (1.f/CC);
  float var  = s2 * (1.f/CC) - mean*mean;
  float rstd = rsqrtf(var + EPS_LN);
  float4 gv = *(const float4*)&g[c0];
  float4 bv = *(const float4*)&be[c0];
  float y0 = (o0-mean)*rstd*gv.x + bv.x;
  float y1 = (o1-mean)*rstd*gv.y + bv.y;
  float y2 = (o2-mean)*rstd*gv.z + bv.z;
  float y3 = (o3-mean)*rstd*gv.w + bv.w;
  float4 yv = {y0,y1,y2,y3};
  *(float4*)&xn[(size_t)pix*CC + c0] = yv;
  ushort4 yb = {f2bf_r(y0), f2bf_r(y1), f2bf_r(y2), f2bf_r(y3)};
  *(ushort4*)&xnb[(size_t)pix*CC + c0] = yb;
}

// ---------------- LayerNorm f32 -> bf16 (one row per block) ----------------
__global__ void k_ln_bf16(const float* __restrict__ X, const float* __restrict__ g,
                          const float* __restrict__ be, bf16u* __restrict__ Y){
  int row = blockIdx.x;
  int t = threadIdx.x;
  float v = X[(size_t)row*CC + t];
  float s = v, s2 = v*v;
#pragma unroll
  for (int off = 32; off; off >>= 1){
    s  += __shfl_down(s,  off);
    s2 += __shfl_down(s2, off);
  }
  __shared__ float red[10];
  int wv_ = t >> 6, ln = t & 63;
  if (ln == 0){ red[wv_] = s; red[4+wv_] = s2; }
  __syncthreads();
  if (t == 0){
    float S  = red[0]+red[1]+red[2]+red[3];
    float S2 = red[4]+red[5]+red[6]+red[7];
    float mean = S * (1.f/CC);
    float var  = S2 * (1.f/CC) - mean*mean;
    red[8] = mean; red[9] = rsqrtf(var + EPS_LN);
  }
  __syncthreads();
  float mean = red[8], rstd = red[9];
  Y[(size_t)row*CC + t] = f2bf_r((v - mean) * rstd * g[t] + be[t]);
}

// ---------------- adaptive avg pool (one (b,p) per block, c = thread) ----------------
__global__ void k_pool(const float* __restrict__ xn, float* __restrict__ praw){
  int bp = blockIdx.x;
  int b = bp / PP, p = bp % PP;
  int ps, pi;
  if (p < 144)      { ps = 12; pi = p; }
  else if (p < 400) { ps = 16; pi = p - 144; }
  else if (p < 800) { ps = 20; pi = p - 400; }
  else              { ps = 24; pi = p - 800; }
  int oi = pi / ps, oj = pi % ps;
  int si = oi*HH/ps, ei = ((oi+1)*HH + ps - 1)/ps;
  int sj = oj*WW/ps, ej = ((oj+1)*WW + ps - 1)/ps;
  int c = threadIdx.x;
  const float* xb = xn + (size_t)b*NN*CC + c;
  float acc = 0.f;
  for (int i = si; i < ei; i++)
    for (int j = sj; j < ej; j++)
      acc += xb[(size_t)(i*WW+j)*CC];
  praw[(size_t)bp*CC + c] = acc / (float)((ei-si)*(ej-sj));
}

// ---------------- pool-dwconv + attn-norm fused -> bf16 ----------------
__global__ void k_pooldw_ln(const float* __restrict__ praw,
    const float* w0, const float* b0, const float* w1, const float* b1,
    const float* w2, const float* b2, const float* w3, const float* b3,
    const float* __restrict__ g, const float* __restrict__ be,
    bf16u* __restrict__ pools){
  int bp = blockIdx.x;
  int b = bp / PP, p = bp % PP;
  int ps, pi, off; const float *w, *bi;
  if (p < 144)      { ps=12; pi=p;     off=0;   w=w0; bi=b0; }
  else if (p < 400) { ps=16; pi=p-144; off=144; w=w1; bi=b1; }
  else if (p < 800) { ps=20; pi=p-400; off=400; w=w2; bi=b2; }
  else              { ps=24; pi=p-800; off=800; w=w3; bi=b3; }
  int oi = pi/ps, oj = pi%ps;
  int c = threadIdx.x;
  const float* base = praw + (size_t)(b*PP + off)*CC + c;
  float acc = bi[c];
#pragma unroll
  for (int kh = 0; kh < 3; kh++){
    int ii = oi + kh - 1; if (ii < 0 || ii >= ps) continue;
#pragma unroll
    for (int kw = 0; kw < 3; kw++){
      int jj = oj + kw - 1; if (jj < 0 || jj >= ps) continue;
      acc += base[(size_t)(ii*ps+jj)*CC] * w[c*9 + kh*3 + kw];
    }
  }
  float v = base[(size_t)(oi*ps+oj)*CC] + acc;
  // block LN over 256 channels
  float s = v, s2 = v*v;
#pragma unroll
  for (int o2_ = 32; o2_; o2_ >>= 1){
    s  += __shfl_down(s,  o2_);
    s2 += __shfl_down(s2, o2_);
  }
  __shared__ float red[10];
  int wv_ = c >> 6, ln = c & 63;
  if (ln == 0){ red[wv_] = s; red[4+wv_] = s2; }
  __syncthreads();
  if (c == 0){
    float S  = red[0]+red[1]+red[2]+red[3];
    float S2 = red[4]+red[5]+red[6]+red[7];
    float mean = S * (1.f/CC);
    float var  = S2 * (1.f/CC) - mean*mean;
    red[8] = mean; red[9] = rsqrtf(var + EPS_LN);
  }
  __syncthreads();
  float mean = red[8], rstd = red[9];
  pools[(size_t)bp*CC + c] = f2bf_r((v - mean) * rstd * g[c] + be[c]);
}

// ===== MFMA GEMM, all-bf16 inputs: Out = act(oscale*(A @ W^T) + bias) (+Res) =====
#define GST 40
template<bool OUT_BF16, bool HAS_BIAS, bool DO_GELU, bool HAS_RES>
__global__ __launch_bounds__(256) void k_gemm_mfma(const bf16u* __restrict__ A,
                       const bf16u* __restrict__ Wt,
                       const float* __restrict__ bias, void* Outp,
                       const float* Res, int M, int Nout, int K, float oscale){
  __shared__ bf16u Ash[128*GST];
  __shared__ bf16u Bsh[128*GST];
  int t = threadIdx.x;
  int wave = t >> 6, lane = t & 63, quad = lane >> 4, l16 = lane & 15;
  int m0 = blockIdx.y * 128, n0 = blockIdx.x * 128;
  int wm = (wave >> 1) * 64, wn = (wave & 1) * 64;
  int srow = t >> 1, scol = (t & 1) * 16;
  f32x4 zero = {0.f,0.f,0.f,0.f};
  f32x4 acc[4][4];
#pragma unroll
  for (int i = 0; i < 4; i++)
#pragma unroll
    for (int j = 0; j < 4; j++) acc[i][j] = zero;
  for (int k0 = 0; k0 < K; k0 += 32){
    __syncthreads();
    {
      const bf16u* ap = A + (size_t)(m0+srow)*K + k0 + scol;
      uint4 u = *(const uint4*)ap;
      uint4 v = *(const uint4*)(ap+8);
      *(uint4*)&Ash[srow*GST + scol]     = u;
      *(uint4*)&Ash[srow*GST + scol + 8] = v;
      const bf16u* bp = Wt + (size_t)(n0+srow)*K + k0 + scol;
      uint4 x = *(const uint4*)bp;
      uint4 y = *(const uint4*)(bp+8);
      *(uint4*)&Bsh[srow*GST + scol]     = x;
      *(uint4*)&Bsh[srow*GST + scol + 8] = y;
    }
    __syncthreads();
    short8 af[4], bfr[4];
#pragma unroll
    for (int mi = 0; mi < 4; mi++)
      af[mi] = *(const short8*)&Ash[(wm + mi*16 + l16)*GST + quad*8];
#pragma unroll
    for (int ni = 0; ni < 4; ni++)
      bfr[ni] = *(const short8*)&Bsh[(wn + ni*16 + l16)*GST + quad*8];
#pragma unroll
    for (int mi = 0; mi < 4; mi++)
#pragma unroll
      for (int ni = 0; ni < 4; ni++)
        acc[mi][ni] = __builtin_amdgcn_mfma_f32_16x16x32_bf16(af[mi], bfr[ni], acc[mi][ni], 0,0,0);
  }
#pragma unroll
  for (int mi = 0; mi < 4; mi++){
#pragma unroll
    for (int r = 0; r < 4; r++){
      int row = m0 + wm + mi*16 + quad*4 + r;
#pragma unroll
      for (int ni = 0; ni < 4; ni++){
        int col = n0 + wn + ni*16 + l16;
        float v = acc[mi][ni][r] * oscale;
        if constexpr (HAS_BIAS) v += bias[col];
        if constexpr (DO_GELU)  v = 0.5f*v*(1.f + erff(v*0.70710678118654752f));
        if constexpr (HAS_RES)  v += Res[(size_t)row*Nout + col];
        if constexpr (OUT_BF16) ((bf16u*)Outp)[(size_t)row*Nout + col] = f2bf_r(v);
        else                    ((float*)Outp)[(size_t)row*Nout + col] = v;
      }
    }
  }
}

// ============ MFMA flash attention: 64 q x 2 heads per block ============
// q pre-scaled by ATT_SCALE*log2(e) in the q-projection -> P = exp2(QK^T), 1 instr.
// 32-key chunks, register prefetch of next chunk, no max-subtraction (|s| small).
#define KST 72   // 144B rows: 16B-aligned, 2-way banks (free)
#define VST 40   // 80B rows
#define PST 40
__global__ __launch_bounds__(256) void k_attn_mfma(const bf16u* __restrict__ q,
                       const bf16u* __restrict__ kv, bf16u* __restrict__ out){
  __shared__ bf16u Ksh[32*KST];     // [key][64 dims (2 heads)]
  __shared__ bf16u Vsh[64*VST];     // [dim][key] (transposed)
  __shared__ bf16u Psh[8][16*PST];  // [wave*2+h][query][key]
  int t = threadIdx.x;
  int wave = t >> 6, lane = t & 63, quad = lane >> 4, l16 = lane & 15;
  int bid = blockIdx.x;
  int qt = bid % (NN/64);
  int hp = (bid / (NN/64)) % (NHEAD/2);
  int b  = bid / ((NN/64)*(NHEAD/2));
  int q0 = qt*64 + wave*16;
  const bf16u* qb = q + (size_t)(b*NN + q0 + l16)*CC + hp*64 + quad*8;
  short8 qf0 = *(const short8*)qb;
  short8 qf1 = *(const short8*)(qb + HD);
  f32x4 zero = {0.f,0.f,0.f,0.f};
  f32x4 o00 = zero, o01 = zero, o10 = zero, o11 = zero;
  float ls0[4] = {0.f,0.f,0.f,0.f}, ls1[4] = {0.f,0.f,0.f,0.f};
  int sp = t & 31, sd0 = (t >> 5) * 8;
  const bf16u* kvp = kv + (size_t)(b*PP + sp)*(2*CC) + hp*64 + sd0;
  uint4 kk = *(const uint4*)kvp;
  uint4 vv = *(const uint4*)(kvp + CC);
  for (int ch = 0; ch < PP/32; ch++){
    __syncthreads();
    *(uint4*)&Ksh[sp*KST + sd0] = kk;
    Vsh[(sd0+0)*VST + sp] = (bf16u)(vv.x & 0xffff);
    Vsh[(sd0+1)*VST + sp] = (bf16u)(vv.x >> 16);
    Vsh[(sd0+2)*VST + sp] = (bf16u)(vv.y & 0xffff);
    Vsh[(sd0+3)*VST + sp] = (bf16u)(vv.y >> 16);
    Vsh[(sd0+4)*VST + sp] = (bf16u)(vv.z & 0xffff);
    Vsh[(sd0+5)*VST + sp] = (bf16u)(vv.z >> 16);
    Vsh[(sd0+6)*VST + sp] = (bf16u)(vv.w & 0xffff);
    Vsh[(sd0+7)*VST + sp] = (bf16u)(vv.w >> 16);
    if (ch < PP/32 - 1){
      kvp += 32*2*CC;
      kk = *(const uint4*)kvp;
      vv = *(const uint4*)(kvp + CC);
    }
    __syncthreads();
    short8 kf00 = *(const short8*)&Ksh[(l16     )*KST +      quad*8];
    short8 kf01 = *(const short8*)&Ksh[(l16 + 16)*KST +      quad*8];
    short8 kf10 = *(const short8*)&Ksh[(l16     )*KST + 32 + quad*8];
    short8 kf11 = *(const short8*)&Ksh[(l16 + 16)*KST + 32 + quad*8];
    f32x4 s00 = __builtin_amdgcn_mfma_f32_16x16x32_bf16(qf0, kf00, zero, 0,0,0);
    f32x4 s01 = __builtin_amdgcn_mfma_f32_16x16x32_bf16(qf0, kf01, zero, 0,0,0);
    f32x4 s10 = __builtin_amdgcn_mfma_f32_16x16x32_bf16(qf1, kf10, zero, 0,0,0);
    f32x4 s11 = __builtin_amdgcn_mfma_f32_16x16x32_bf16(qf1, kf11, zero, 0,0,0);
    bf16u* P0 = &Psh[wave*2+0][0];
    bf16u* P1 = &Psh[wave*2+1][0];
#pragma unroll
    for (int r = 0; r < 4; r++){
      float e00 = exp2f(s00[r]), e01 = exp2f(s01[r]);
      float e10 = exp2f(s10[r]), e11 = exp2f(s11[r]);
      ls0[r] += e00 + e01; ls1[r] += e10 + e11;
      P0[(quad*4+r)*PST + l16     ] = f2bf_r(e00);
      P0[(quad*4+r)*PST + l16 + 16] = f2bf_r(e01);
      P1[(quad*4+r)*PST + l16     ] = f2bf_r(e10);
      P1[(quad*4+r)*PST + l16 + 16] = f2bf_r(e11);
    }
    short8 pf0 = *(const short8*)&P0[l16*PST + quad*8];
    short8 pf1 = *(const short8*)&P1[l16*PST + quad*8];
    short8 vf00 = *(const short8*)&Vsh[(     l16)*VST + quad*8];
    short8 vf01 = *(const short8*)&Vsh[(16 + l16)*VST + quad*8];
    short8 vf10 = *(const short8*)&Vsh[(32 + l16)*VST + quad*8];
    short8 vf11 = *(const short8*)&Vsh[(48 + l16)*VST + quad*8];
    o00 = __builtin_amdgcn_mfma_f32_16x16x32_bf16(pf0, vf00, o00, 0,0,0);
    o01 = __builtin_amdgcn_mfma_f32_16x16x32_bf16(pf0, vf01, o01, 0,0,0);
    o10 = __builtin_amdgcn_mfma_f32_16x16x32_bf16(pf1, vf10, o10, 0,0,0);
    o11 = __builtin_amdgcn_mfma_f32_16x16x32_bf16(pf1, vf11, o11, 0,0,0);
  }
#pragma unroll
  for (int r = 0; r < 4; r++){
    float s0 = ls0[r], s1 = ls1[r];
    s0 += __shfl_xor(s0,1); s0 += __shfl_xor(s0,2);
    s0 += __shfl_xor(s0,4); s0 += __shfl_xor(s0,8);
    s1 += __shfl_xor(s1,1); s1 += __shfl_xor(s1,2);
    s1 += __shfl_xor(s1,4); s1 += __shfl_xor(s1,8);
    ls0[r] = s0; ls1[r] = s1;
  }
#pragma unroll
  for (int r = 0; r < 4; r++){
    size_t base = (size_t)(b*NN + q0 + quad*4 + r)*CC + hp*64;
    float i0 = 1.f/ls0[r], i1 = 1.f/ls1[r];
    out[base + l16     ] = f2bf_r(o00[r]*i0);
    out[base + 16 + l16] = f2bf_r(o01[r]*i0);
    out[base + 32 + l16] = f2bf_r(o10[r]*i1);
    out[base + 48 + l16] = f2bf_r(o11[r]*i1);
  }
}

// ---------------- h2 = h + dwconv3x3(h) + bias  (hid=1024, bf16, vectorized) ----------------
__global__ void k_dwh(const bf16u* __restrict__ h, const float* __restrict__ w,
                      const float* __restrict__ bias, bf16u* __restrict__ h2){
  int pix = blockIdx.x;
  int b = pix / NN, n = pix % NN;
  int hy = n / WW, wx = n % WW;
  int c0 = threadIdx.x * 4;
  float wv[4][9];
  float acc[4];
#pragma unroll
  for (int cc = 0; cc < 4; cc++){
    acc[cc] = bias[c0+cc];
#pragma unroll
    for (int k = 0; k < 9; k++) wv[cc][k] = w[(c0+cc)*9 + k];
  }
  const bf16u* hb = h + (size_t)b*NN*HIDN + c0;
#pragma unroll
  for (int kh = 0; kh < 3; kh++){
    int iy = hy + kh - 1; if (iy < 0 || iy >= HH) continue;
#pragma unroll
    for (int kw = 0; kw < 3; kw++){
      int ix = wx + kw - 1; if (ix < 0 || ix >= WW) continue;
      ushort4 hv = *(const ushort4*)&hb[(size_t)(iy*WW+ix)*HIDN];
      int k = kh*3+kw;
      acc[0] += bf2f(hv.x)*wv[0][k]; acc[1] += bf2f(hv.y)*wv[1][k];
      acc[2] += bf2f(hv.z)*wv[2][k]; acc[3] += bf2f(hv.w)*wv[3][k];
    }
  }
  ushort4 cv = *(const ushort4*)&hb[(size_t)n*HIDN];
  ushort4 o;
  o.x = f2bf_r(bf2f(cv.x) + acc[0]); o.y = f2bf_r(bf2f(cv.y) + acc[1]);
  o.z = f2bf_r(bf2f(cv.z) + acc[2]); o.w = f2bf_r(bf2f(cv.w) + acc[3]);
  *(ushort4*)&h2[(size_t)pix*HIDN + c0] = o;
}

extern "C" void kernel_launch(void* const* d_in, const int* in_sizes, int n_in,
                              void* d_out, int out_size, void* d_ws, size_t ws_size,
                              hipStream_t stream){
  const float* x      = (const float*)d_in[0];
  const float* cpe_w  = (const float*)d_in[1];
  const float* cpe_b  = (const float*)d_in[2];
  const float* n1w    = (const float*)d_in[3];
  const float* n1b    = (const float*)d_in[4];
  const float* q_w    = (const float*)d_in[5];
  const float* kv_w   = (const float*)d_in[6];
  const float* anw    = (const float*)d_in[7];
  const float* anb    = (const float*)d_in[8];
  const float* proj_w = (const float*)d_in[9];
  const float* proj_b = (const float*)d_in[10];
  const float* n2w    = (const float*)d_in[11];
  const float* n2b    = (const float*)d_in[12];
  const float* fc1_w  = (const float*)d_in[13];
  const float* fc1_b  = (const float*)d_in[14];
  const float* irb_w  = (const float*)d_in[15];
  const float* irb_b  = (const float*)d_in[16];
  const float* fc2_w  = (const float*)d_in[17];
  const float* fc2_b  = (const float*)d_in[18];
  const float* dw0    = (const float*)d_in[21];
  const float* db0    = (const float*)d_in[22];
  const float* dw1    = (const float*)d_in[23];
  const float* db1    = (const float*)d_in[24];
  const float* dw2    = (const float*)d_in[25];
  const float* db2    = (const float*)d_in[26];
  const float* dw3    = (const float*)d_in[27];
  const float* db3    = (const float*)d_in[28];

  const size_t BNC = (size_t)BQ*NN*CC;       // 3,211,264
  const size_t BPC = (size_t)BQ*PP*CC;       // 1,409,024
  const size_t BNH = (size_t)BQ*NN*HIDN;     // 12,845,056

  // layout: x1 f32 | xnb bf16 | W bf16 (786432) | region A
  //   A phase1: xn f32 | qb bf16 | praw f32 | poolsb bf16 | kvb bf16
  //   A phase2 (overlay): hbuf bf16 | h2buf bf16     (~72 MB total)
  float* x1   = (float*)d_ws;
  bf16u* xnb  = (bf16u*)(x1 + BNC);
  bf16u* wbuf = xnb + BNC;
  bf16u* wq   = wbuf;
  bf16u* wkv  = wbuf + 65536;
  bf16u* wpj  = wbuf + 196608;
  bf16u* wf1  = wbuf + 262144;
  bf16u* wf2  = wbuf + 524288;
  float* A0   = (float*)(wbuf + 786432);
  float* xn   = A0;
  bf16u* qb   = (bf16u*)(xn + BNC);
  float* praw = (float*)(qb + BNC);
  bf16u* poolsb = (bf16u*)(praw + BPC);
  bf16u* kvb  = poolsb + BPC;
  bf16u* hbuf = (bf16u*)A0;          // phase-2 overlay
  bf16u* h2buf = hbuf + BNH;

  // 0. weights -> bf16 (once per call)
  k_wconv<<<768, 256, 0, stream>>>(q_w, kv_w, proj_w, fc1_w, fc2_w, wbuf);
  // 1. CPE + residual + norm1 (writes x1 f32, xn f32, xnb bf16)
  k_cpe_ln<<<BQ*NN/4, 256, 0, stream>>>(x, cpe_w, cpe_b, n1w, n1b, x1, xn, xnb);
  // 2. q projection -> bf16, pre-scaled by ATT_SCALE*log2e
  k_gemm_mfma<true,false,false,false><<<dim3(CC/128, BQ*NN/128), 256, 0, stream>>>(
      xnb, wq, nullptr, qb, nullptr, BQ*NN, CC, CC, QSCALE_LOG2E);
  // 3. pyramid pooling
  k_pool<<<BQ*PP, 256, 0, stream>>>(xn, praw);
  // 4. pool dwconv + attn-norm -> bf16
  k_pooldw_ln<<<BQ*PP, 256, 0, stream>>>(praw, dw0,db0, dw1,db1, dw2,db2, dw3,db3,
                                         anw, anb, poolsb);
  // 5. kv projection -> bf16
  k_gemm_mfma<true,false,false,false><<<dim3(2*CC/128, BQ*PP/128), 256, 0, stream>>>(
      poolsb, wkv, nullptr, kvb, nullptr, BQ*PP, 2*CC, CC, 1.0f);
  // 6. MFMA attention (in-place: qb becomes attn output)
  k_attn_mfma<<<BQ*(NHEAD/2)*(NN/64), 256, 0, stream>>>(qb, kvb, qb);
  // 7. proj + bias + residual -> x1 (f32)
  k_gemm_mfma<false,true,false,true><<<dim3(CC/128, BQ*NN/128), 256, 0, stream>>>(
      qb, wpj, proj_b, x1, x1, BQ*NN, CC, CC, 1.0f);
  // 8. norm2 -> bf16 (xnb reuse)
  k_ln_bf16<<<BQ*NN, 256, 0, stream>>>(x1, n2w, n2b, xnb);
  // 9. fc1 + bias + gelu -> hbuf (bf16)
  k_gemm_mfma<true,true,true,false><<<dim3(HIDN/128, BQ*NN/128), 256, 0, stream>>>(
      xnb, wf1, fc1_b, hbuf, nullptr, BQ*NN, HIDN, CC, 1.0f);
  // 10. h2 = h + dwconv(h)
  k_dwh<<<BQ*NN, 256, 0, stream>>>(hbuf, irb_w, irb_b, h2buf);
  // 11. fc2 + bias + residual -> d_out (f32)
  k_gemm_mfma<false,true,false,true><<<dim3(CC/128, BQ*NN/128), 256, 0, stream>>>(
      h2buf, wf2, fc2_b, d_out, x1, BQ*NN, CC, HIDN, 1.0f);
}

// Round 8
// 430.254 us; speedup vs baseline: 2.6841x; 1.0051x over previous
//
#include <hip/hip_runtime.h>
#include <hip/hip_bf16.h>

#define BQ 4
#define HH 56
#define WW 56
#define NN (HH*WW)      // 3136
#define CC 256
#define NHEAD 8
#define HD 32
#define PP 1376
#define HIDN 1024
#define EPS_LN 1e-5f
// ATT_SCALE * log2(e): scores from QK^T come out ready for exp2
#define QSCALE_LOG2E 0.25503484f

typedef unsigned short bf16u;
typedef __attribute__((ext_vector_type(8))) short short8;
typedef __attribute__((ext_vector_type(4))) float f32x4;

__device__ __forceinline__ float bf2f(bf16u u){
  union { unsigned int i; float f; } v; v.i = ((unsigned int)u) << 16; return v.f;
}
__device__ __forceinline__ bf16u f2bf(float f){
  unsigned int x = __float_as_uint(f);
  x += 0x7fffu + ((x >> 16) & 1u);
  return (bf16u)(x >> 16);
}
// cheap half-up round (2 ops) for hot paths
__device__ __forceinline__ bf16u f2bf_r(float f){
  return (bf16u)((__float_as_uint(f) + 0x8000u) >> 16);
}

// ---------------- weights -> bf16, once per launch ----------------
__global__ void k_wconv(const float* __restrict__ qw, const float* __restrict__ kvw,
                        const float* __restrict__ pw, const float* __restrict__ f1,
                        const float* __restrict__ f2, bf16u* __restrict__ o){
  int off = (blockIdx.x*256 + threadIdx.x) * 4;
  const float* s;
  if (off < 65536)       s = qw  + off;
  else if (off < 196608) s = kvw + off - 65536;
  else if (off < 262144) s = pw  + off - 196608;
  else if (off < 524288) s = f1  + off - 262144;
  else                   s = f2  + off - 524288;
  float4 v = *(const float4*)s;
  ushort4 u = {f2bf(v.x), f2bf(v.y), f2bf(v.z), f2bf(v.w)};
  *(ushort4*)(o + off) = u;
}

// ---------------- CPE + norm1 fused ----------------
__global__ void k_cpe_ln(const float* __restrict__ x, const float* __restrict__ w,
                         const float* __restrict__ bias, const float* __restrict__ g,
                         const float* __restrict__ be, float* __restrict__ x1,
                         float* __restrict__ xn, bf16u* __restrict__ xnb){
  int t = threadIdx.x;
  int pix = blockIdx.x*4 + (t >> 6);
  int b = pix / NN, n = pix % NN;
  int hy = n / WW, wx = n % WW;
  int c0 = (t & 63) * 4;
  float wv[4][9];
  float acc[4];
#pragma unroll
  for (int cc = 0; cc < 4; cc++){
    acc[cc] = bias[c0+cc];
#pragma unroll
    for (int k = 0; k < 9; k++) wv[cc][k] = w[(c0+cc)*9 + k];
  }
  const float* xb = x + (size_t)b*NN*CC + c0;
#pragma unroll
  for (int kh = 0; kh < 3; kh++){
    int iy = hy + kh - 1;
    if (iy < 0 || iy >= HH) continue;
#pragma unroll
    for (int kw = 0; kw < 3; kw++){
      int ix = wx + kw - 1;
      if (ix < 0 || ix >= WW) continue;
      float4 v = *(const float4*)&xb[(size_t)(iy*WW+ix)*CC];
      int k = kh*3+kw;
      acc[0] += v.x*wv[0][k]; acc[1] += v.y*wv[1][k];
      acc[2] += v.z*wv[2][k]; acc[3] += v.w*wv[3][k];
    }
  }
  float4 cv = *(const float4*)&xb[(size_t)n*CC];
  float o0 = cv.x + acc[0], o1 = cv.y + acc[1];
  float o2 = cv.z + acc[2], o3 = cv.w + acc[3];
  float4 ov = {o0,o1,o2,o3};
  *(float4*)&x1[(size_t)pix*CC + c0] = ov;
  float s  = o0+o1+o2+o3;
  float s2 = o0*o0+o1*o1+o2*o2+o3*o3;
#pragma unroll
  for (int off = 32; off; off >>= 1){
    s  += __shfl_xor(s,  off);
    s2 += __shfl_xor(s2, off);
  }
  float mean = s * (1.f/CC);
  float var  = s2 * (1.f/CC) - mean*mean;
  float rstd = rsqrtf(var + EPS_LN);
  float4 gv = *(const float4*)&g[c0];
  float4 bv = *(const float4*)&be[c0];
  float y0 = (o0-mean)*rstd*gv.x + bv.x;
  float y1 = (o1-mean)*rstd*gv.y + bv.y;
  float y2 = (o2-mean)*rstd*gv.z + bv.z;
  float y3 = (o3-mean)*rstd*gv.w + bv.w;
  float4 yv = {y0,y1,y2,y3};
  *(float4*)&xn[(size_t)pix*CC + c0] = yv;
  ushort4 yb = {f2bf_r(y0), f2bf_r(y1), f2bf_r(y2), f2bf_r(y3)};
  *(ushort4*)&xnb[(size_t)pix*CC + c0] = yb;
}

// ---------------- LayerNorm f32 -> bf16 ----------------
__global__ void k_ln_bf16(const float* __restrict__ X, const float* __restrict__ g,
                          const float* __restrict__ be, bf16u* __restrict__ Y){
  int row = blockIdx.x;
  int t = threadIdx.x;
  float v = X[(size_t)row*CC + t];
  float s = v, s2 = v*v;
#pragma unroll
  for (int off = 32; off; off >>= 1){
    s  += __shfl_down(s,  off);
    s2 += __shfl_down(s2, off);
  }
  __shared__ float red[10];
  int wv_ = t >> 6, ln = t & 63;
  if (ln == 0){ red[wv_] = s; red[4+wv_] = s2; }
  __syncthreads();
  if (t == 0){
    float S  = red[0]+red[1]+red[2]+red[3];
    float S2 = red[4]+red[5]+red[6]+red[7];
    float mean = S * (1.f/CC);
    float var  = S2 * (1.f/CC) - mean*mean;
    red[8] = mean; red[9] = rsqrtf(var + EPS_LN);
  }
  __syncthreads();
  float mean = red[8], rstd = red[9];
  Y[(size_t)row*CC + t] = f2bf_r((v - mean) * rstd * g[t] + be[t]);
}

// ---------------- adaptive avg pool ----------------
__global__ void k_pool(const float* __restrict__ xn, float* __restrict__ praw){
  int bp = blockIdx.x;
  int b = bp / PP, p = bp % PP;
  int ps, pi;
  if (p < 144)      { ps = 12; pi = p; }
  else if (p < 400) { ps = 16; pi = p - 144; }
  else if (p < 800) { ps = 20; pi = p - 400; }
  else              { ps = 24; pi = p - 800; }
  int oi = pi / ps, oj = pi % ps;
  int si = oi*HH/ps, ei = ((oi+1)*HH + ps - 1)/ps;
  int sj = oj*WW/ps, ej = ((oj+1)*WW + ps - 1)/ps;
  int c = threadIdx.x;
  const float* xb = xn + (size_t)b*NN*CC + c;
  float acc = 0.f;
  for (int i = si; i < ei; i++)
    for (int j = sj; j < ej; j++)
      acc += xb[(size_t)(i*WW+j)*CC];
  praw[(size_t)bp*CC + c] = acc / (float)((ei-si)*(ej-sj));
}

// ---------------- pool-dwconv + attn-norm fused -> bf16 ----------------
__global__ void k_pooldw_ln(const float* __restrict__ praw,
    const float* w0, const float* b0, const float* w1, const float* b1,
    const float* w2, const float* b2, const float* w3, const float* b3,
    const float* __restrict__ g, const float* __restrict__ be,
    bf16u* __restrict__ pools){
  int bp = blockIdx.x;
  int b = bp / PP, p = bp % PP;
  int ps, pi, off; const float *w, *bi;
  if (p < 144)      { ps=12; pi=p;     off=0;   w=w0; bi=b0; }
  else if (p < 400) { ps=16; pi=p-144; off=144; w=w1; bi=b1; }
  else if (p < 800) { ps=20; pi=p-400; off=400; w=w2; bi=b2; }
  else              { ps=24; pi=p-800; off=800; w=w3; bi=b3; }
  int oi = pi/ps, oj = pi%ps;
  int c = threadIdx.x;
  const float* base = praw + (size_t)(b*PP + off)*CC + c;
  float acc = bi[c];
#pragma unroll
  for (int kh = 0; kh < 3; kh++){
    int ii = oi + kh - 1; if (ii < 0 || ii >= ps) continue;
#pragma unroll
    for (int kw = 0; kw < 3; kw++){
      int jj = oj + kw - 1; if (jj < 0 || jj >= ps) continue;
      acc += base[(size_t)(ii*ps+jj)*CC] * w[c*9 + kh*3 + kw];
    }
  }
  float v = base[(size_t)(oi*ps+oj)*CC] + acc;
  float s = v, s2 = v*v;
#pragma unroll
  for (int o2_ = 32; o2_; o2_ >>= 1){
    s  += __shfl_down(s,  o2_);
    s2 += __shfl_down(s2, o2_);
  }
  __shared__ float red[10];
  int wv_ = c >> 6, ln = c & 63;
  if (ln == 0){ red[wv_] = s; red[4+wv_] = s2; }
  __syncthreads();
  if (c == 0){
    float S  = red[0]+red[1]+red[2]+red[3];
    float S2 = red[4]+red[5]+red[6]+red[7];
    float mean = S * (1.f/CC);
    float var  = S2 * (1.f/CC) - mean*mean;
    red[8] = mean; red[9] = rsqrtf(var + EPS_LN);
  }
  __syncthreads();
  float mean = red[8], rstd = red[9];
  pools[(size_t)bp*CC + c] = f2bf_r((v - mean) * rstd * g[c] + be[c]);
}

// ===== MFMA GEMM, bf16: Out = act(oscale*(A @ W^T) + bias) (+Res); NT = 128 or 64 =====
#define GST 40
template<int NT, bool OUT_BF16, bool HAS_BIAS, bool DO_GELU, bool HAS_RES>
__global__ __launch_bounds__(256) void k_gemm_mfma(const bf16u* __restrict__ A,
                       const bf16u* __restrict__ Wt,
                       const float* __restrict__ bias, void* Outp,
                       const float* Res, int M, int Nout, int K, float oscale){
  constexpr int NW = (NT == 128) ? 4 : 2;   // n-frags per wave
  __shared__ bf16u Ash[128*GST];
  __shared__ bf16u Bsh[NT*GST];
  int t = threadIdx.x;
  int wave = t >> 6, lane = t & 63, quad = lane >> 4, l16 = lane & 15;
  int m0 = blockIdx.y * 128, n0 = blockIdx.x * NT;
  int wm = (wave >> 1) * 64;
  int wn = (wave & 1) * (NT/2);
  int srow = t >> 1, scol = (t & 1) * 16;
  f32x4 zero = {0.f,0.f,0.f,0.f};
  f32x4 acc[4][NW];
#pragma unroll
  for (int i = 0; i < 4; i++)
#pragma unroll
    for (int j = 0; j < NW; j++) acc[i][j] = zero;
  for (int k0 = 0; k0 < K; k0 += 32){
    __syncthreads();
    {
      const bf16u* ap = A + (size_t)(m0+srow)*K + k0 + scol;
      uint4 u = *(const uint4*)ap;
      uint4 v = *(const uint4*)(ap+8);
      *(uint4*)&Ash[srow*GST + scol]     = u;
      *(uint4*)&Ash[srow*GST + scol + 8] = v;
    }
    if constexpr (NT == 128){
      const bf16u* bp = Wt + (size_t)(n0+srow)*K + k0 + scol;
      uint4 u = *(const uint4*)bp;
      uint4 v = *(const uint4*)(bp+8);
      *(uint4*)&Bsh[srow*GST + scol]     = u;
      *(uint4*)&Bsh[srow*GST + scol + 8] = v;
    } else {
      int br = t >> 2, bc = (t & 3) * 8;
      const bf16u* bp = Wt + (size_t)(n0+br)*K + k0 + bc;
      uint4 u = *(const uint4*)bp;
      *(uint4*)&Bsh[br*GST + bc] = u;
    }
    __syncthreads();
    short8 af[4], bfr[NW];
#pragma unroll
    for (int mi = 0; mi < 4; mi++)
      af[mi] = *(const short8*)&Ash[(wm + mi*16 + l16)*GST + quad*8];
#pragma unroll
    for (int ni = 0; ni < NW; ni++)
      bfr[ni] = *(const short8*)&Bsh[(wn + ni*16 + l16)*GST + quad*8];
#pragma unroll
    for (int mi = 0; mi < 4; mi++)
#pragma unroll
      for (int ni = 0; ni < NW; ni++)
        acc[mi][ni] = __builtin_amdgcn_mfma_f32_16x16x32_bf16(af[mi], bfr[ni], acc[mi][ni], 0,0,0);
  }
#pragma unroll
  for (int mi = 0; mi < 4; mi++){
#pragma unroll
    for (int r = 0; r < 4; r++){
      int row = m0 + wm + mi*16 + quad*4 + r;
#pragma unroll
      for (int ni = 0; ni < NW; ni++){
        int col = n0 + wn + ni*16 + l16;
        float v = acc[mi][ni][r] * oscale;
        if constexpr (HAS_BIAS) v += bias[col];
        if constexpr (DO_GELU)  v = 0.5f*v*(1.f + erff(v*0.70710678118654752f));
        if constexpr (HAS_RES)  v += Res[(size_t)row*Nout + col];
        if constexpr (OUT_BF16) ((bf16u*)Outp)[(size_t)row*Nout + col] = f2bf_r(v);
        else                    ((float*)Outp)[(size_t)row*Nout + col] = v;
      }
    }
  }
}

// ============ MFMA flash attention: 64 q x 2 heads per block ============
// QK^T computed TRANSPOSED (A=K, B=Q): C-frag gives each lane 4 consecutive keys
// for its own q=l16 -> P packs to b64 LDS writes; PV reads P as A-frag same-wave
// (no barrier; DS ops are wave-ordered). V de-interleave uses rotated write order
// so the 4 dim-groups hit distinct banks (kills the 8-way conflict).
#define KST 72   // K rows [key][64 dims], 144B
#define VST 40   // V^T rows [dim][32 keys], 80B
#define PST 40   // P rows [q][32 keys], 80B
__global__ __launch_bounds__(256) void k_attn_mfma(const bf16u* __restrict__ q,
                       const bf16u* __restrict__ kv, bf16u* __restrict__ out){
  __shared__ bf16u Ksh[32*KST];
  __shared__ bf16u Vsh[64*VST];
  __shared__ bf16u Psh[4][2][16*PST];   // [wave][head][q][key]
  int t = threadIdx.x;
  int wave = t >> 6, lane = t & 63, quad = lane >> 4, l16 = lane & 15;
  int bid = blockIdx.x;
  int qt = bid % (NN/64);
  int hp = (bid / (NN/64)) % (NHEAD/2);
  int b  = bid / ((NN/64)*(NHEAD/2));
  int q0 = qt*64 + wave*16;
  // Q B-frag: lane holds Q[q=l16][dim quad*8+j] (pre-scaled by QSCALE_LOG2E)
  const bf16u* qptr = q + (size_t)(b*NN + q0 + l16)*CC + hp*64 + quad*8;
  short8 qf0 = *(const short8*)qptr;
  short8 qf1 = *(const short8*)(qptr + HD);
  f32x4 zero = {0.f,0.f,0.f,0.f};
  f32x4 o00 = zero, o01 = zero, o10 = zero, o11 = zero;
  float ls0 = 0.f, ls1 = 0.f;
  int sp = t & 31, dgrp = t >> 5, sd0 = dgrp*8;
  const bf16u* kvp = kv + (size_t)(b*PP + sp)*(2*CC) + hp*64 + sd0;
  uint4 kk = *(const uint4*)kvp;
  uint4 vv = *(const uint4*)(kvp + CC);
  for (int ch = 0; ch < PP/32; ch++){
    __syncthreads();
    *(uint4*)&Ksh[sp*KST + sd0] = kk;
    {
      ushort va[8] = {(ushort)(vv.x & 0xffff),(ushort)(vv.x >> 16),
                      (ushort)(vv.y & 0xffff),(ushort)(vv.y >> 16),
                      (ushort)(vv.z & 0xffff),(ushort)(vv.z >> 16),
                      (ushort)(vv.w & 0xffff),(ushort)(vv.w >> 16)};
#pragma unroll
      for (int i = 0; i < 8; i++){
        int ii = (i + dgrp) & 7;                  // rotate: distinct banks across dgrp
        Vsh[(sd0+ii)*VST + sp] = va[ii];
      }
    }
    if (ch < PP/32 - 1){
      kvp += 32*2*CC;
      kk = *(const uint4*)kvp;
      vv = *(const uint4*)(kvp + CC);
    }
    __syncthreads();
    // K A-frags (per head, per 16-key block)
    short8 kf00 = *(const short8*)&Ksh[(l16     )*KST +      quad*8];
    short8 kf01 = *(const short8*)&Ksh[(16 + l16)*KST +      quad*8];
    short8 kf10 = *(const short8*)&Ksh[(l16     )*KST + 32 + quad*8];
    short8 kf11 = *(const short8*)&Ksh[(16 + l16)*KST + 32 + quad*8];
    // S^T = K·Q^T: lane holds S[q=l16][key = blk*16 + quad*4 + r]
    f32x4 s00 = __builtin_amdgcn_mfma_f32_16x16x32_bf16(kf00, qf0, zero, 0,0,0);
    f32x4 s01 = __builtin_amdgcn_mfma_f32_16x16x32_bf16(kf01, qf0, zero, 0,0,0);
    f32x4 s10 = __builtin_amdgcn_mfma_f32_16x16x32_bf16(kf10, qf1, zero, 0,0,0);
    f32x4 s11 = __builtin_amdgcn_mfma_f32_16x16x32_bf16(kf11, qf1, zero, 0,0,0);
    // exp2 + pack 4 consecutive keys -> one b64 write each
    float e0a = exp2f(s00[0]), e0b = exp2f(s00[1]), e0c = exp2f(s00[2]), e0d = exp2f(s00[3]);
    float e1a = exp2f(s01[0]), e1b = exp2f(s01[1]), e1c = exp2f(s01[2]), e1d = exp2f(s01[3]);
    float f0a = exp2f(s10[0]), f0b = exp2f(s10[1]), f0c = exp2f(s10[2]), f0d = exp2f(s10[3]);
    float f1a = exp2f(s11[0]), f1b = exp2f(s11[1]), f1c = exp2f(s11[2]), f1d = exp2f(s11[3]);
    ls0 += (e0a+e0b)+(e0c+e0d) + (e1a+e1b)+(e1c+e1d);
    ls1 += (f0a+f0b)+(f0c+f0d) + (f1a+f1b)+(f1c+f1d);
    ushort4 p00 = {f2bf_r(e0a), f2bf_r(e0b), f2bf_r(e0c), f2bf_r(e0d)};
    ushort4 p01 = {f2bf_r(e1a), f2bf_r(e1b), f2bf_r(e1c), f2bf_r(e1d)};
    ushort4 p10 = {f2bf_r(f0a), f2bf_r(f0b), f2bf_r(f0c), f2bf_r(f0d)};
    ushort4 p11 = {f2bf_r(f1a), f2bf_r(f1b), f2bf_r(f1c), f2bf_r(f1d)};
    bf16u* P0 = &Psh[wave][0][0];
    bf16u* P1 = &Psh[wave][1][0];
    *(ushort4*)&P0[l16*PST +      quad*4] = p00;
    *(ushort4*)&P0[l16*PST + 16 + quad*4] = p01;
    *(ushort4*)&P1[l16*PST +      quad*4] = p10;
    *(ushort4*)&P1[l16*PST + 16 + quad*4] = p11;
    // P A-frag (same-wave: DS ordering guarantees visibility, no barrier)
    short8 pf0 = *(const short8*)&P0[l16*PST + quad*8];
    short8 pf1 = *(const short8*)&P1[l16*PST + quad*8];
    // V B-frags
    short8 vf00 = *(const short8*)&Vsh[(     l16)*VST + quad*8];
    short8 vf01 = *(const short8*)&Vsh[(16 + l16)*VST + quad*8];
    short8 vf10 = *(const short8*)&Vsh[(32 + l16)*VST + quad*8];
    short8 vf11 = *(const short8*)&Vsh[(48 + l16)*VST + quad*8];
    // O[m=q][n=d]: lane gets O[q=quad*4+r][d = blk*16 + l16]
    o00 = __builtin_amdgcn_mfma_f32_16x16x32_bf16(pf0, vf00, o00, 0,0,0);
    o01 = __builtin_amdgcn_mfma_f32_16x16x32_bf16(pf0, vf01, o01, 0,0,0);
    o10 = __builtin_amdgcn_mfma_f32_16x16x32_bf16(pf1, vf10, o10, 0,0,0);
    o11 = __builtin_amdgcn_mfma_f32_16x16x32_bf16(pf1, vf11, o11, 0,0,0);
  }
  // L[q=l16]: reduce partials across the 4 quads
  ls0 += __shfl_xor(ls0, 16); ls0 += __shfl_xor(ls0, 32);
  ls1 += __shfl_xor(ls1, 16); ls1 += __shfl_xor(ls1, 32);
#pragma unroll
  for (int r = 0; r < 4; r++){
    int qq = quad*4 + r;
    float i0 = 1.f / __shfl(ls0, qq);   // lane qq (quad0,l16=qq) holds L[qq]
    float i1 = 1.f / __shfl(ls1, qq);
    size_t base = (size_t)(b*NN + q0 + qq)*CC + hp*64;
    out[base + l16     ] = f2bf_r(o00[r]*i0);
    out[base + 16 + l16] = f2bf_r(o01[r]*i0);
    out[base + 32 + l16] = f2bf_r(o10[r]*i1);
    out[base + 48 + l16] = f2bf_r(o11[r]*i1);
  }
}

// ---------------- h2 = h + dwconv3x3(h) + bias (hid=1024, bf16) ----------------
__global__ void k_dwh(const bf16u* __restrict__ h, const float* __restrict__ w,
                      const float* __restrict__ bias, bf16u* __restrict__ h2){
  int pix = blockIdx.x;
  int b = pix / NN, n = pix % NN;
  int hy = n / WW, wx = n % WW;
  int c0 = threadIdx.x * 4;
  float wv[4][9];
  float acc[4];
#pragma unroll
  for (int cc = 0; cc < 4; cc++){
    acc[cc] = bias[c0+cc];
#pragma unroll
    for (int k = 0; k < 9; k++) wv[cc][k] = w[(c0+cc)*9 + k];
  }
  const bf16u* hb = h + (size_t)b*NN*HIDN + c0;
#pragma unroll
  for (int kh = 0; kh < 3; kh++){
    int iy = hy + kh - 1; if (iy < 0 || iy >= HH) continue;
#pragma unroll
    for (int kw = 0; kw < 3; kw++){
      int ix = wx + kw - 1; if (ix < 0 || ix >= WW) continue;
      ushort4 hv = *(const ushort4*)&hb[(size_t)(iy*WW+ix)*HIDN];
      int k = kh*3+kw;
      acc[0] += bf2f(hv.x)*wv[0][k]; acc[1] += bf2f(hv.y)*wv[1][k];
      acc[2] += bf2f(hv.z)*wv[2][k]; acc[3] += bf2f(hv.w)*wv[3][k];
    }
  }
  ushort4 cv = *(const ushort4*)&hb[(size_t)n*HIDN];
  ushort4 o;
  o.x = f2bf_r(bf2f(cv.x) + acc[0]); o.y = f2bf_r(bf2f(cv.y) + acc[1]);
  o.z = f2bf_r(bf2f(cv.z) + acc[2]); o.w = f2bf_r(bf2f(cv.w) + acc[3]);
  *(ushort4*)&h2[(size_t)pix*HIDN + c0] = o;
}

extern "C" void kernel_launch(void* const* d_in, const int* in_sizes, int n_in,
                              void* d_out, int out_size, void* d_ws, size_t ws_size,
                              hipStream_t stream){
  const float* x      = (const float*)d_in[0];
  const float* cpe_w  = (const float*)d_in[1];
  const float* cpe_b  = (const float*)d_in[2];
  const float* n1w    = (const float*)d_in[3];
  const float* n1b    = (const float*)d_in[4];
  const float* q_w    = (const float*)d_in[5];
  const float* kv_w   = (const float*)d_in[6];
  const float* anw    = (const float*)d_in[7];
  const float* anb    = (const float*)d_in[8];
  const float* proj_w = (const float*)d_in[9];
  const float* proj_b = (const float*)d_in[10];
  const float* n2w    = (const float*)d_in[11];
  const float* n2b    = (const float*)d_in[12];
  const float* fc1_w  = (const float*)d_in[13];
  const float* fc1_b  = (const float*)d_in[14];
  const float* irb_w  = (const float*)d_in[15];
  const float* irb_b  = (const float*)d_in[16];
  const float* fc2_w  = (const float*)d_in[17];
  const float* fc2_b  = (const float*)d_in[18];
  const float* dw0    = (const float*)d_in[21];
  const float* db0    = (const float*)d_in[22];
  const float* dw1    = (const float*)d_in[23];
  const float* db1    = (const float*)d_in[24];
  const float* dw2    = (const float*)d_in[25];
  const float* db2    = (const float*)d_in[26];
  const float* dw3    = (const float*)d_in[27];
  const float* db3    = (const float*)d_in[28];

  const size_t BNC = (size_t)BQ*NN*CC;
  const size_t BPC = (size_t)BQ*PP*CC;
  const size_t BNH = (size_t)BQ*NN*HIDN;

  float* x1   = (float*)d_ws;
  bf16u* xnb  = (bf16u*)(x1 + BNC);
  bf16u* wbuf = xnb + BNC;
  bf16u* wq   = wbuf;
  bf16u* wkv  = wbuf + 65536;
  bf16u* wpj  = wbuf + 196608;
  bf16u* wf1  = wbuf + 262144;
  bf16u* wf2  = wbuf + 524288;
  float* A0   = (float*)(wbuf + 786432);
  float* xn   = A0;
  bf16u* qb   = (bf16u*)(xn + BNC);
  float* praw = (float*)(qb + BNC);
  bf16u* poolsb = (bf16u*)(praw + BPC);
  bf16u* kvb  = poolsb + BPC;
  bf16u* hbuf = (bf16u*)A0;          // phase-2 overlay
  bf16u* h2buf = hbuf + BNH;

  // 0. weights -> bf16
  k_wconv<<<768, 256, 0, stream>>>(q_w, kv_w, proj_w, fc1_w, fc2_w, wbuf);
  // 1. CPE + residual + norm1
  k_cpe_ln<<<BQ*NN/4, 256, 0, stream>>>(x, cpe_w, cpe_b, n1w, n1b, x1, xn, xnb);
  // 2. q projection -> bf16 (pre-scaled), NT=64
  k_gemm_mfma<64,true,false,false,false><<<dim3(CC/64, BQ*NN/128), 256, 0, stream>>>(
      xnb, wq, nullptr, qb, nullptr, BQ*NN, CC, CC, QSCALE_LOG2E);
  // 3. pyramid pooling
  k_pool<<<BQ*PP, 256, 0, stream>>>(xn, praw);
  // 4. pool dwconv + attn-norm -> bf16
  k_pooldw_ln<<<BQ*PP, 256, 0, stream>>>(praw, dw0,db0, dw1,db1, dw2,db2, dw3,db3,
                                         anw, anb, poolsb);
  // 5. kv projection -> bf16, NT=64
  k_gemm_mfma<64,true,false,false,false><<<dim3(2*CC/64, BQ*PP/128), 256, 0, stream>>>(
      poolsb, wkv, nullptr, kvb, nullptr, BQ*PP, 2*CC, CC, 1.0f);
  // 6. MFMA attention (in-place: qb becomes attn output)
  k_attn_mfma<<<BQ*(NHEAD/2)*(NN/64), 256, 0, stream>>>(qb, kvb, qb);
  // 7. proj + bias + residual -> x1, NT=64
  k_gemm_mfma<64,false,true,false,true><<<dim3(CC/64, BQ*NN/128), 256, 0, stream>>>(
      qb, wpj, proj_b, x1, x1, BQ*NN, CC, CC, 1.0f);
  // 8. norm2 -> bf16
  k_ln_bf16<<<BQ*NN, 256, 0, stream>>>(x1, n2w, n2b, xnb);
  // 9. fc1 + bias + gelu -> hbuf (bf16), NT=128
  k_gemm_mfma<128,true,true,true,false><<<dim3(HIDN/128, BQ*NN/128), 256, 0, stream>>>(
      xnb, wf1, fc1_b, hbuf, nullptr, BQ*NN, HIDN, CC, 1.0f);
  // 10. h2 = h + dwconv(h)
  k_dwh<<<BQ*NN, 256, 0, stream>>>(hbuf, irb_w, irb_b, h2buf);
  // 11. fc2 + bias + residual -> d_out (f32), NT=64
  k_gemm_mfma<64,false,true,false,true><<<dim3(CC/64, BQ*NN/128), 256, 0, stream>>>(
      h2buf, wf2, fc2_b, d_out, x1, BQ*NN, CC, HIDN, 1.0f);
}

// Round 9
// 412.981 us; speedup vs baseline: 2.7964x; 1.0418x over previous
//
#include <hip/hip_runtime.h>
#include <hip/hip_bf16.h>

#define BQ 4
#define HH 56
#define WW 56
#define NN (HH*WW)      // 3136
#define CC 256
#define NHEAD 8
#define HD 32
#define PP 1376
#define PPAD 1408       // 22 * 64
#define HIDN 1024
#define EPS_LN 1e-5f
// ATT_SCALE * log2(e): scores from QK^T come out ready for exp2
#define QSCALE_LOG2E 0.25503484f

typedef unsigned short bf16u;
typedef __attribute__((ext_vector_type(8))) short short8;
typedef __attribute__((ext_vector_type(4))) float f32x4;

__device__ __forceinline__ float bf2f(bf16u u){
  union { unsigned int i; float f; } v; v.i = ((unsigned int)u) << 16; return v.f;
}
__device__ __forceinline__ bf16u f2bf(float f){
  unsigned int x = __float_as_uint(f);
  x += 0x7fffu + ((x >> 16) & 1u);
  return (bf16u)(x >> 16);
}
// cheap half-up round (2 ops) for hot paths
__device__ __forceinline__ bf16u f2bf_r(float f){
  return (bf16u)((__float_as_uint(f) + 0x8000u) >> 16);
}

// ---------------- weights -> bf16, once per launch ----------------
__global__ void k_wconv(const float* __restrict__ qw, const float* __restrict__ kvw,
                        const float* __restrict__ pw, const float* __restrict__ f1,
                        const float* __restrict__ f2, bf16u* __restrict__ o){
  int off = (blockIdx.x*256 + threadIdx.x) * 4;
  const float* s;
  if (off < 65536)       s = qw  + off;
  else if (off < 196608) s = kvw + off - 65536;
  else if (off < 262144) s = pw  + off - 196608;
  else if (off < 524288) s = f1  + off - 262144;
  else                   s = f2  + off - 524288;
  float4 v = *(const float4*)s;
  ushort4 u = {f2bf(v.x), f2bf(v.y), f2bf(v.z), f2bf(v.w)};
  *(ushort4*)(o + off) = u;
}

// ---------------- CPE + norm1 fused ----------------
__global__ void k_cpe_ln(const float* __restrict__ x, const float* __restrict__ w,
                         const float* __restrict__ bias, const float* __restrict__ g,
                         const float* __restrict__ be, float* __restrict__ x1,
                         float* __restrict__ xn, bf16u* __restrict__ xnb){
  int t = threadIdx.x;
  int pix = blockIdx.x*4 + (t >> 6);
  int b = pix / NN, n = pix % NN;
  int hy = n / WW, wx = n % WW;
  int c0 = (t & 63) * 4;
  float wv[4][9];
  float acc[4];
#pragma unroll
  for (int cc = 0; cc < 4; cc++){
    acc[cc] = bias[c0+cc];
#pragma unroll
    for (int k = 0; k < 9; k++) wv[cc][k] = w[(c0+cc)*9 + k];
  }
  const float* xb = x + (size_t)b*NN*CC + c0;
#pragma unroll
  for (int kh = 0; kh < 3; kh++){
    int iy = hy + kh - 1;
    if (iy < 0 || iy >= HH) continue;
#pragma unroll
    for (int kw = 0; kw < 3; kw++){
      int ix = wx + kw - 1;
      if (ix < 0 || ix >= WW) continue;
      float4 v = *(const float4*)&xb[(size_t)(iy*WW+ix)*CC];
      int k = kh*3+kw;
      acc[0] += v.x*wv[0][k]; acc[1] += v.y*wv[1][k];
      acc[2] += v.z*wv[2][k]; acc[3] += v.w*wv[3][k];
    }
  }
  float4 cv = *(const float4*)&xb[(size_t)n*CC];
  float o0 = cv.x + acc[0], o1 = cv.y + acc[1];
  float o2 = cv.z + acc[2], o3 = cv.w + acc[3];
  float4 ov = {o0,o1,o2,o3};
  *(float4*)&x1[(size_t)pix*CC + c0] = ov;
  float s  = o0+o1+o2+o3;
  float s2 = o0*o0+o1*o1+o2*o2+o3*o3;
#pragma unroll
  for (int off = 32; off; off >>= 1){
    s  += __shfl_xor(s,  off);
    s2 += __shfl_xor(s2, off);
  }
  float mean = s * (1.f/CC);
  float var  = s2 * (1.f/CC) - mean*mean;
  float rstd = rsqrtf(var + EPS_LN);
  float4 gv = *(const float4*)&g[c0];
  float4 bv = *(const float4*)&be[c0];
  float y0 = (o0-mean)*rstd*gv.x + bv.x;
  float y1 = (o1-mean)*rstd*gv.y + bv.y;
  float y2 = (o2-mean)*rstd*gv.z + bv.z;
  float y3 = (o3-mean)*rstd*gv.w + bv.w;
  float4 yv = {y0,y1,y2,y3};
  *(float4*)&xn[(size_t)pix*CC + c0] = yv;
  ushort4 yb = {f2bf_r(y0), f2bf_r(y1), f2bf_r(y2), f2bf_r(y3)};
  *(ushort4*)&xnb[(size_t)pix*CC + c0] = yb;
}

// ---------------- LayerNorm f32 -> bf16 ----------------
__global__ void k_ln_bf16(const float* __restrict__ X, const float* __restrict__ g,
                          const float* __restrict__ be, bf16u* __restrict__ Y){
  int row = blockIdx.x;
  int t = threadIdx.x;
  float v = X[(size_t)row*CC + t];
  float s = v, s2 = v*v;
#pragma unroll
  for (int off = 32; off; off >>= 1){
    s  += __shfl_down(s,  off);
    s2 += __shfl_down(s2, off);
  }
  __shared__ float red[10];
  int wv_ = t >> 6, ln = t & 63;
  if (ln == 0){ red[wv_] = s; red[4+wv_] = s2; }
  __syncthreads();
  if (t == 0){
    float S  = red[0]+red[1]+red[2]+red[3];
    float S2 = red[4]+red[5]+red[6]+red[7];
    float mean = S * (1.f/CC);
    float var  = S2 * (1.f/CC) - mean*mean;
    red[8] = mean; red[9] = rsqrtf(var + EPS_LN);
  }
  __syncthreads();
  float mean = red[8], rstd = red[9];
  Y[(size_t)row*CC + t] = f2bf_r((v - mean) * rstd * g[t] + be[t]);
}

// ---------------- adaptive avg pool ----------------
__global__ void k_pool(const float* __restrict__ xn, float* __restrict__ praw){
  int bp = blockIdx.x;
  int b = bp / PP, p = bp % PP;
  int ps, pi;
  if (p < 144)      { ps = 12; pi = p; }
  else if (p < 400) { ps = 16; pi = p - 144; }
  else if (p < 800) { ps = 20; pi = p - 400; }
  else              { ps = 24; pi = p - 800; }
  int oi = pi / ps, oj = pi % ps;
  int si = oi*HH/ps, ei = ((oi+1)*HH + ps - 1)/ps;
  int sj = oj*WW/ps, ej = ((oj+1)*WW + ps - 1)/ps;
  int c = threadIdx.x;
  const float* xb = xn + (size_t)b*NN*CC + c;
  float acc = 0.f;
  for (int i = si; i < ei; i++)
    for (int j = sj; j < ej; j++)
      acc += xb[(size_t)(i*WW+j)*CC];
  praw[(size_t)bp*CC + c] = acc / (float)((ei-si)*(ej-sj));
}

// ---------------- pool-dwconv + attn-norm fused -> bf16 ----------------
__global__ void k_pooldw_ln(const float* __restrict__ praw,
    const float* w0, const float* b0, const float* w1, const float* b1,
    const float* w2, const float* b2, const float* w3, const float* b3,
    const float* __restrict__ g, const float* __restrict__ be,
    bf16u* __restrict__ pools){
  int bp = blockIdx.x;
  int b = bp / PP, p = bp % PP;
  int ps, pi, off; const float *w, *bi;
  if (p < 144)      { ps=12; pi=p;     off=0;   w=w0; bi=b0; }
  else if (p < 400) { ps=16; pi=p-144; off=144; w=w1; bi=b1; }
  else if (p < 800) { ps=20; pi=p-400; off=400; w=w2; bi=b2; }
  else              { ps=24; pi=p-800; off=800; w=w3; bi=b3; }
  int oi = pi/ps, oj = pi%ps;
  int c = threadIdx.x;
  const float* base = praw + (size_t)(b*PP + off)*CC + c;
  float acc = bi[c];
#pragma unroll
  for (int kh = 0; kh < 3; kh++){
    int ii = oi + kh - 1; if (ii < 0 || ii >= ps) continue;
#pragma unroll
    for (int kw = 0; kw < 3; kw++){
      int jj = oj + kw - 1; if (jj < 0 || jj >= ps) continue;
      acc += base[(size_t)(ii*ps+jj)*CC] * w[c*9 + kh*3 + kw];
    }
  }
  float v = base[(size_t)(oi*ps+oj)*CC] + acc;
  float s = v, s2 = v*v;
#pragma unroll
  for (int o2_ = 32; o2_; o2_ >>= 1){
    s  += __shfl_down(s,  o2_);
    s2 += __shfl_down(s2, o2_);
  }
  __shared__ float red[10];
  int wv_ = c >> 6, ln = c & 63;
  if (ln == 0){ red[wv_] = s; red[4+wv_] = s2; }
  __syncthreads();
  if (c == 0){
    float S  = red[0]+red[1]+red[2]+red[3];
    float S2 = red[4]+red[5]+red[6]+red[7];
    float mean = S * (1.f/CC);
    float var  = S2 * (1.f/CC) - mean*mean;
    red[8] = mean; red[9] = rsqrtf(var + EPS_LN);
  }
  __syncthreads();
  float mean = red[8], rstd = red[9];
  pools[(size_t)bp*CC + c] = f2bf_r((v - mean) * rstd * g[c] + be[c]);
}

// ===== MFMA GEMM, bf16: Out = act(oscale*(A @ W^T) + bias) (+Res); NT = 128 or 64 =====
#define GST 40
template<int NT, bool OUT_BF16, bool HAS_BIAS, bool DO_GELU, bool HAS_RES>
__global__ __launch_bounds__(256) void k_gemm_mfma(const bf16u* __restrict__ A,
                       const bf16u* __restrict__ Wt,
                       const float* __restrict__ bias, void* Outp,
                       const float* Res, int M, int Nout, int K, float oscale){
  constexpr int NW = (NT == 128) ? 4 : 2;
  __shared__ bf16u Ash[128*GST];
  __shared__ bf16u Bsh[NT*GST];
  int t = threadIdx.x;
  int wave = t >> 6, lane = t & 63, quad = lane >> 4, l16 = lane & 15;
  int m0 = blockIdx.y * 128, n0 = blockIdx.x * NT;
  int wm = (wave >> 1) * 64;
  int wn = (wave & 1) * (NT/2);
  int srow = t >> 1, scol = (t & 1) * 16;
  f32x4 zero = {0.f,0.f,0.f,0.f};
  f32x4 acc[4][NW];
#pragma unroll
  for (int i = 0; i < 4; i++)
#pragma unroll
    for (int j = 0; j < NW; j++) acc[i][j] = zero;
  for (int k0 = 0; k0 < K; k0 += 32){
    __syncthreads();
    {
      const bf16u* ap = A + (size_t)(m0+srow)*K + k0 + scol;
      uint4 u = *(const uint4*)ap;
      uint4 v = *(const uint4*)(ap+8);
      *(uint4*)&Ash[srow*GST + scol]     = u;
      *(uint4*)&Ash[srow*GST + scol + 8] = v;
    }
    if constexpr (NT == 128){
      const bf16u* bp = Wt + (size_t)(n0+srow)*K + k0 + scol;
      uint4 u = *(const uint4*)bp;
      uint4 v = *(const uint4*)(bp+8);
      *(uint4*)&Bsh[srow*GST + scol]     = u;
      *(uint4*)&Bsh[srow*GST + scol + 8] = v;
    } else {
      int br = t >> 2, bc = (t & 3) * 8;
      const bf16u* bp = Wt + (size_t)(n0+br)*K + k0 + bc;
      uint4 u = *(const uint4*)bp;
      *(uint4*)&Bsh[br*GST + bc] = u;
    }
    __syncthreads();
    short8 af[4], bfr[NW];
#pragma unroll
    for (int mi = 0; mi < 4; mi++)
      af[mi] = *(const short8*)&Ash[(wm + mi*16 + l16)*GST + quad*8];
#pragma unroll
    for (int ni = 0; ni < NW; ni++)
      bfr[ni] = *(const short8*)&Bsh[(wn + ni*16 + l16)*GST + quad*8];
#pragma unroll
    for (int mi = 0; mi < 4; mi++)
#pragma unroll
      for (int ni = 0; ni < NW; ni++)
        acc[mi][ni] = __builtin_amdgcn_mfma_f32_16x16x32_bf16(af[mi], bfr[ni], acc[mi][ni], 0,0,0);
  }
#pragma unroll
  for (int mi = 0; mi < 4; mi++){
#pragma unroll
    for (int r = 0; r < 4; r++){
      int row = m0 + wm + mi*16 + quad*4 + r;
#pragma unroll
      for (int ni = 0; ni < NW; ni++){
        int col = n0 + wn + ni*16 + l16;
        float v = acc[mi][ni][r] * oscale;
        if constexpr (HAS_BIAS) v += bias[col];
        if constexpr (DO_GELU)  v = 0.5f*v*(1.f + erff(v*0.70710678118654752f));
        if constexpr (HAS_RES)  v += Res[(size_t)row*Nout + col];
        if constexpr (OUT_BF16) ((bf16u*)Outp)[(size_t)row*Nout + col] = f2bf_r(v);
        else                    ((float*)Outp)[(size_t)row*Nout + col] = v;
      }
    }
  }
}

// ---------------- V transpose: kvb[b][p][256+d] -> vt[b][d][p] ----------------
// read 16B coalesced, scatter 2B writes (L2 write-combines; 2.8 MB total)
__global__ void k_vt(const bf16u* __restrict__ kvb, bf16u* __restrict__ vt){
  int gid = blockIdx.x*256 + threadIdx.x;   // BQ*PPAD*32 total
  int p  = (gid >> 5) % PPAD;
  int b  = (gid >> 5) / PPAD;
  int dc = (gid & 31) * 8;
  const bf16u* src = kvb + ((size_t)(b*PP + p)*(2*CC) + CC + dc);
  ushort4 u0 = *(const ushort4*)src;
  ushort4 u1 = *(const ushort4*)(src+4);
  bf16u* dst = vt + ((size_t)(b*CC + dc)*PPAD + p);
  dst[0*PPAD]=u0.x; dst[1*PPAD]=u0.y; dst[2*PPAD]=u0.z; dst[3*PPAD]=u0.w;
  dst[4*PPAD]=u1.x; dst[5*PPAD]=u1.y; dst[6*PPAD]=u1.z; dst[7*PPAD]=u1.w;
}

// ============ MFMA flash attention: 64 q x 2 heads per block, 64-key chunks ============
// K staged from kvb [p][dims]; V staged from pre-transposed vt [d][p] — both pure
// uint4 copies (no de-interleave). S^T orientation (A=K, B=Q): lane holds 4 consecutive
// keys for q=l16 -> b64 P writes, read back as A-frag same-wave (no barrier).
// Tail chunk (p0=1344) masks keys >= PP by skipping score-blocks 2,3 (1344+32 == PP).
#define KST 72
#define VST 72
#define PST 72
__global__ __launch_bounds__(256) void k_attn_mfma(const bf16u* __restrict__ q,
                       const bf16u* __restrict__ kvb, const bf16u* __restrict__ vt,
                       bf16u* __restrict__ out){
  __shared__ bf16u Ksh[64*KST];          // [key][64 dims (2 heads)]
  __shared__ bf16u Vsh[64*VST];          // [d (2 heads x 32)][64 keys]
  __shared__ bf16u Psh[4][2][16*PST];    // [wave][head][q][64 keys]
  int t = threadIdx.x;
  int wave = t >> 6, lane = t & 63, quad = lane >> 4, l16 = lane & 15;
  int bid = blockIdx.x;
  int qt = bid % (NN/64);
  int hp = (bid / (NN/64)) % (NHEAD/2);
  int b  = bid / ((NN/64)*(NHEAD/2));
  int q0 = qt*64 + wave*16;
  const bf16u* qptr = q + (size_t)(b*NN + q0 + l16)*CC + hp*64 + quad*8;
  short8 qf0 = *(const short8*)qptr;
  short8 qf1 = *(const short8*)(qptr + HD);
  f32x4 zero = {0.f,0.f,0.f,0.f};
  f32x4 o00 = zero, o01 = zero, o10 = zero, o11 = zero;  // [head][d-block]
  float ls0 = 0.f, ls1 = 0.f;
  int sr = t >> 2, sc = (t & 3) * 16;
  const bf16u* ksrc = kvb + (size_t)(b*PP + sr)*(2*CC) + hp*64 + sc;
  const bf16u* vsrc = vt  + (size_t)(b*CC + hp*64 + sr)*PPAD + sc;
  uint4 ka = *(const uint4*)ksrc, kb = *(const uint4*)(ksrc+8);
  uint4 va = *(const uint4*)vsrc, vb = *(const uint4*)(vsrc+8);

#define DO_BLK(blk) { \
    short8 kf0 = *(const short8*)&Ksh[(blk*16 + l16)*KST + quad*8]; \
    short8 kf1 = *(const short8*)&Ksh[(blk*16 + l16)*KST + 32 + quad*8]; \
    f32x4 s0 = __builtin_amdgcn_mfma_f32_16x16x32_bf16(kf0, qf0, zero, 0,0,0); \
    f32x4 s1 = __builtin_amdgcn_mfma_f32_16x16x32_bf16(kf1, qf1, zero, 0,0,0); \
    float e0a = exp2f(s0[0]), e0b = exp2f(s0[1]), e0c = exp2f(s0[2]), e0d = exp2f(s0[3]); \
    float e1a = exp2f(s1[0]), e1b = exp2f(s1[1]), e1c = exp2f(s1[2]), e1d = exp2f(s1[3]); \
    ls0 += (e0a+e0b)+(e0c+e0d); ls1 += (e1a+e1b)+(e1c+e1d); \
    ushort4 pa = {f2bf_r(e0a), f2bf_r(e0b), f2bf_r(e0c), f2bf_r(e0d)}; \
    ushort4 pb = {f2bf_r(e1a), f2bf_r(e1b), f2bf_r(e1c), f2bf_r(e1d)}; \
    *(ushort4*)&P0[l16*PST + blk*16 + quad*4] = pa; \
    *(ushort4*)&P1[l16*PST + blk*16 + quad*4] = pb; }

#define DO_PV(kc) { \
    short8 pf0 = *(const short8*)&P0[l16*PST + kc*32 + quad*8]; \
    short8 pf1 = *(const short8*)&P1[l16*PST + kc*32 + quad*8]; \
    short8 vf00 = *(const short8*)&Vsh[(     l16)*VST + kc*32 + quad*8]; \
    short8 vf01 = *(const short8*)&Vsh[(16 + l16)*VST + kc*32 + quad*8]; \
    short8 vf10 = *(const short8*)&Vsh[(32 + l16)*VST + kc*32 + quad*8]; \
    short8 vf11 = *(const short8*)&Vsh[(48 + l16)*VST + kc*32 + quad*8]; \
    o00 = __builtin_amdgcn_mfma_f32_16x16x32_bf16(pf0, vf00, o00, 0,0,0); \
    o01 = __builtin_amdgcn_mfma_f32_16x16x32_bf16(pf0, vf01, o01, 0,0,0); \
    o10 = __builtin_amdgcn_mfma_f32_16x16x32_bf16(pf1, vf10, o10, 0,0,0); \
    o11 = __builtin_amdgcn_mfma_f32_16x16x32_bf16(pf1, vf11, o11, 0,0,0); }

  for (int ch = 0; ch < PPAD/64; ch++){
    __syncthreads();
    *(uint4*)&Ksh[sr*KST + sc]     = ka;
    *(uint4*)&Ksh[sr*KST + sc + 8] = kb;
    *(uint4*)&Vsh[sr*VST + sc]     = va;
    *(uint4*)&Vsh[sr*VST + sc + 8] = vb;
    if (ch < PPAD/64 - 1){
      ksrc += (size_t)64*(2*CC); vsrc += 64;
      ka = *(const uint4*)ksrc; kb = *(const uint4*)(ksrc+8);
      va = *(const uint4*)vsrc; vb = *(const uint4*)(vsrc+8);
    }
    __syncthreads();
    bf16u* P0 = &Psh[wave][0][0];
    bf16u* P1 = &Psh[wave][1][0];
    if (ch < PPAD/64 - 1){
      DO_BLK(0) DO_BLK(1) DO_BLK(2) DO_BLK(3)
      DO_PV(0) DO_PV(1)
    } else {
      // tail: keys p0+0..31 valid (1344..1375), 32..63 masked off entirely
      DO_BLK(0) DO_BLK(1)
      DO_PV(0)
    }
  }
#undef DO_BLK
#undef DO_PV
  ls0 += __shfl_xor(ls0, 16); ls0 += __shfl_xor(ls0, 32);
  ls1 += __shfl_xor(ls1, 16); ls1 += __shfl_xor(ls1, 32);
#pragma unroll
  for (int r = 0; r < 4; r++){
    int qq = quad*4 + r;
    float i0 = 1.f / __shfl(ls0, qq);
    float i1 = 1.f / __shfl(ls1, qq);
    size_t base = (size_t)(b*NN + q0 + qq)*CC + hp*64;
    out[base + l16     ] = f2bf_r(o00[r]*i0);
    out[base + 16 + l16] = f2bf_r(o01[r]*i0);
    out[base + 32 + l16] = f2bf_r(o10[r]*i1);
    out[base + 48 + l16] = f2bf_r(o11[r]*i1);
  }
}

// ---------------- h2 = h + dwconv3x3(h) + bias (hid=1024, bf16) ----------------
__global__ void k_dwh(const bf16u* __restrict__ h, const float* __restrict__ w,
                      const float* __restrict__ bias, bf16u* __restrict__ h2){
  int pix = blockIdx.x;
  int b = pix / NN, n = pix % NN;
  int hy = n / WW, wx = n % WW;
  int c0 = threadIdx.x * 4;
  float wv[4][9];
  float acc[4];
#pragma unroll
  for (int cc = 0; cc < 4; cc++){
    acc[cc] = bias[c0+cc];
#pragma unroll
    for (int k = 0; k < 9; k++) wv[cc][k] = w[(c0+cc)*9 + k];
  }
  const bf16u* hb = h + (size_t)b*NN*HIDN + c0;
#pragma unroll
  for (int kh = 0; kh < 3; kh++){
    int iy = hy + kh - 1; if (iy < 0 || iy >= HH) continue;
#pragma unroll
    for (int kw = 0; kw < 3; kw++){
      int ix = wx + kw - 1; if (ix < 0 || ix >= WW) continue;
      ushort4 hv = *(const ushort4*)&hb[(size_t)(iy*WW+ix)*HIDN];
      int k = kh*3+kw;
      acc[0] += bf2f(hv.x)*wv[0][k]; acc[1] += bf2f(hv.y)*wv[1][k];
      acc[2] += bf2f(hv.z)*wv[2][k]; acc[3] += bf2f(hv.w)*wv[3][k];
    }
  }
  ushort4 cv = *(const ushort4*)&hb[(size_t)n*HIDN];
  ushort4 o;
  o.x = f2bf_r(bf2f(cv.x) + acc[0]); o.y = f2bf_r(bf2f(cv.y) + acc[1]);
  o.z = f2bf_r(bf2f(cv.z) + acc[2]); o.w = f2bf_r(bf2f(cv.w) + acc[3]);
  *(ushort4*)&h2[(size_t)pix*HIDN + c0] = o;
}

extern "C" void kernel_launch(void* const* d_in, const int* in_sizes, int n_in,
                              void* d_out, int out_size, void* d_ws, size_t ws_size,
                              hipStream_t stream){
  const float* x      = (const float*)d_in[0];
  const float* cpe_w  = (const float*)d_in[1];
  const float* cpe_b  = (const float*)d_in[2];
  const float* n1w    = (const float*)d_in[3];
  const float* n1b    = (const float*)d_in[4];
  const float* q_w    = (const float*)d_in[5];
  const float* kv_w   = (const float*)d_in[6];
  const float* anw    = (const float*)d_in[7];
  const float* anb    = (const float*)d_in[8];
  const float* proj_w = (const float*)d_in[9];
  const float* proj_b = (const float*)d_in[10];
  const float* n2w    = (const float*)d_in[11];
  const float* n2b    = (const float*)d_in[12];
  const float* fc1_w  = (const float*)d_in[13];
  const float* fc1_b  = (const float*)d_in[14];
  const float* irb_w  = (const float*)d_in[15];
  const float* irb_b  = (const float*)d_in[16];
  const float* fc2_w  = (const float*)d_in[17];
  const float* fc2_b  = (const float*)d_in[18];
  const float* dw0    = (const float*)d_in[21];
  const float* db0    = (const float*)d_in[22];
  const float* dw1    = (const float*)d_in[23];
  const float* db1    = (const float*)d_in[24];
  const float* dw2    = (const float*)d_in[25];
  const float* db2    = (const float*)d_in[26];
  const float* dw3    = (const float*)d_in[27];
  const float* db3    = (const float*)d_in[28];

  const size_t BNC = (size_t)BQ*NN*CC;
  const size_t BPC = (size_t)BQ*PP*CC;
  const size_t BNH = (size_t)BQ*NN*HIDN;

  float* x1   = (float*)d_ws;
  bf16u* xnb  = (bf16u*)(x1 + BNC);
  bf16u* wbuf = xnb + BNC;
  bf16u* wq   = wbuf;
  bf16u* wkv  = wbuf + 65536;
  bf16u* wpj  = wbuf + 196608;
  bf16u* wf1  = wbuf + 262144;
  bf16u* wf2  = wbuf + 524288;
  float* A0   = (float*)(wbuf + 786432);
  float* xn   = A0;
  bf16u* qb   = (bf16u*)(xn + BNC);
  float* praw = (float*)(qb + BNC);
  bf16u* poolsb = (bf16u*)(praw + BPC);
  bf16u* kvb  = poolsb + BPC;                 // [BQ*PP][512]
  bf16u* vtb  = kvb + (size_t)BQ*PP*2*CC;     // [BQ*256][PPAD]
  bf16u* hbuf = (bf16u*)A0;                   // phase-2 overlay
  bf16u* h2buf = hbuf + BNH;

  // 0. weights -> bf16
  k_wconv<<<768, 256, 0, stream>>>(q_w, kv_w, proj_w, fc1_w, fc2_w, wbuf);
  // 1. CPE + residual + norm1
  k_cpe_ln<<<BQ*NN/4, 256, 0, stream>>>(x, cpe_w, cpe_b, n1w, n1b, x1, xn, xnb);
  // 2. q projection -> bf16 (pre-scaled), NT=64
  k_gemm_mfma<64,true,false,false,false><<<dim3(CC/64, BQ*NN/128), 256, 0, stream>>>(
      xnb, wq, nullptr, qb, nullptr, BQ*NN, CC, CC, QSCALE_LOG2E);
  // 3. pyramid pooling
  k_pool<<<BQ*PP, 256, 0, stream>>>(xn, praw);
  // 4. pool dwconv + attn-norm -> bf16
  k_pooldw_ln<<<BQ*PP, 256, 0, stream>>>(praw, dw0,db0, dw1,db1, dw2,db2, dw3,db3,
                                         anw, anb, poolsb);
  // 5. kv projection -> bf16, NT=64
  k_gemm_mfma<64,true,false,false,false><<<dim3(2*CC/64, BQ*PP/128), 256, 0, stream>>>(
      poolsb, wkv, nullptr, kvb, nullptr, BQ*PP, 2*CC, CC, 1.0f);
  // 5b. V transpose -> vt[b][d][p]
  k_vt<<<BQ*PPAD*32/256, 256, 0, stream>>>(kvb, vtb);
  // 6. MFMA attention (in-place: qb becomes attn output)
  k_attn_mfma<<<BQ*(NHEAD/2)*(NN/64), 256, 0, stream>>>(qb, kvb, vtb, qb);
  // 7. proj + bias + residual -> x1, NT=64
  k_gemm_mfma<64,false,true,false,true><<<dim3(CC/64, BQ*NN/128), 256, 0, stream>>>(
      qb, wpj, proj_b, x1, x1, BQ*NN, CC, CC, 1.0f);
  // 8. norm2 -> bf16
  k_ln_bf16<<<BQ*NN, 256, 0, stream>>>(x1, n2w, n2b, xnb);
  // 9. fc1 + bias + gelu -> hbuf (bf16), NT=128
  k_gemm_mfma<128,true,true,true,false><<<dim3(HIDN/128, BQ*NN/128), 256, 0, stream>>>(
      xnb, wf1, fc1_b, hbuf, nullptr, BQ*NN, HIDN, CC, 1.0f);
  // 10. h2 = h + dwconv(h)
  k_dwh<<<BQ*NN, 256, 0, stream>>>(hbuf, irb_w, irb_b, h2buf);
  // 11. fc2 + bias + residual -> d_out (f32), NT=64
  k_gemm_mfma<64,false,true,false,true><<<dim3(CC/64, BQ*NN/128), 256, 0, stream>>>(
      h2buf, wf2, fc2_b, d_out, x1, BQ*NN, CC, HIDN, 1.0f);
}